// Round 1
// baseline (6782.868 us; speedup 1.0000x reference)
//
#include <hip/hip_runtime.h>

#define NN 200000
#define NE 3200000
#define NG 400

// ---------------- degree ----------------
__global__ void deg_kernel(const int* __restrict__ dst, int* __restrict__ deg) {
    int stride = gridDim.x * blockDim.x;
    for (int e = blockIdx.x * blockDim.x + threadIdx.x; e < NE; e += stride)
        atomicAdd(&deg[dst[e]], 1);
}

__global__ void inv_kernel(const int* __restrict__ deg, float* __restrict__ inv) {
    int stride = gridDim.x * blockDim.x;
    for (int n = blockIdx.x * blockDim.x + threadIdx.x; n < NN; n += stride)
        inv[n] = 1.0f / fmaxf((float)deg[n], 1.0f);
}

// ---------------- edge aggregation (segment_sum of x[src] into agg[dst]) ----
// D % 4 == 0 variant: one thread per (edge, float4-chunk)
template<int D>
__global__ void edge_agg_v4(const int* __restrict__ src, const int* __restrict__ dst,
                            const float* __restrict__ x, float* __restrict__ agg) {
    constexpr int Q = D / 4;
    const int total = NE * Q;
    int stride = gridDim.x * blockDim.x;
    for (int tid = blockIdx.x * blockDim.x + threadIdx.x; tid < total; tid += stride) {
        int e = tid / Q;
        int q = tid - e * Q;
        int s = src[e], d = dst[e];
        const float4 v = *(const float4*)(x + (size_t)s * D + q * 4);
        float* p = agg + (size_t)d * D + q * 4;
        unsafeAtomicAdd(p + 0, v.x);
        unsafeAtomicAdd(p + 1, v.y);
        unsafeAtomicAdd(p + 2, v.z);
        unsafeAtomicAdd(p + 3, v.w);
    }
}

// D == 5 scalar variant
__global__ void edge_agg_d5(const int* __restrict__ src, const int* __restrict__ dst,
                            const float* __restrict__ x, float* __restrict__ agg) {
    const int total = NE * 5;
    int stride = gridDim.x * blockDim.x;
    for (int tid = blockIdx.x * blockDim.x + threadIdx.x; tid < total; tid += stride) {
        int e = tid / 5;
        int j = tid - e * 5;
        int s = src[e], d = dst[e];
        unsafeAtomicAdd(&agg[(size_t)d * 5 + j], x[(size_t)s * 5 + j]);
    }
}

// ---------------- layer 0: out = relu(feat@Ws + inv*(agg@Wn) + b), 32->128 --
__global__ void layer0_kernel(const float* __restrict__ feat, const float* __restrict__ agg,
                              const float* __restrict__ Ws, const float* __restrict__ Wn,
                              const float* __restrict__ bias, const float* __restrict__ inv,
                              float* __restrict__ out) {
    const int total = NN * 128;
    int stride = gridDim.x * blockDim.x;
    for (int tid = blockIdx.x * blockDim.x + threadIdx.x; tid < total; tid += stride) {
        int n = tid >> 7;
        int j = tid & 127;
        const float* f = feat + (size_t)n * 32;
        const float* a = agg + (size_t)n * 32;
        float accS = 0.f, accN = 0.f;
        #pragma unroll 8
        for (int k = 0; k < 32; ++k) {
            accS = fmaf(f[k], Ws[k * 128 + j], accS);
            accN = fmaf(a[k], Wn[k * 128 + j], accN);
        }
        float r = accS + inv[n] * accN + bias[j];
        out[tid] = fmaxf(r, 0.f);
    }
}

// ---------------- dual projection: hs = h@Ws, hn = h@Wn ----------------
template<int DIN, int DOUT>
__global__ void proj_dual_kernel(const float* __restrict__ h,
                                 const float* __restrict__ Ws, const float* __restrict__ Wn,
                                 float* __restrict__ hs, float* __restrict__ hn) {
    const int total = NN * DOUT;
    int stride = gridDim.x * blockDim.x;
    for (int tid = blockIdx.x * blockDim.x + threadIdx.x; tid < total; tid += stride) {
        int n = tid / DOUT;
        int j = tid - n * DOUT;
        const float* r = h + (size_t)n * DIN;
        float accS = 0.f, accN = 0.f;
        #pragma unroll 8
        for (int k = 0; k < DIN; ++k) {
            float v = r[k];
            accS = fmaf(v, Ws[k * DOUT + j], accS);
            accN = fmaf(v, Wn[k * DOUT + j], accN);
        }
        hs[tid] = accS;
        hn[tid] = accN;
    }
}

// ---------------- combine: out = act(hs + inv*agg + b) ----------------
template<int D, bool RELU>
__global__ void combine_kernel(const float* __restrict__ hs, const float* __restrict__ agg,
                               const float* __restrict__ bias, const float* __restrict__ inv,
                               float* __restrict__ out) {
    const int total = NN * D;
    int stride = gridDim.x * blockDim.x;
    for (int tid = blockIdx.x * blockDim.x + threadIdx.x; tid < total; tid += stride) {
        int n = tid / D;
        int j = tid - n * D;
        float r = hs[tid] + inv[n] * agg[tid] + bias[j];
        out[tid] = RELU ? fmaxf(r, 0.f) : r;
    }
}

// ---------------- per-graph mean readout ----------------
__global__ void readout_acc(const float* __restrict__ h, const int* __restrict__ gid,
                            float* __restrict__ tot, float* __restrict__ cnt) {
    int stride = gridDim.x * blockDim.x;
    for (int n = blockIdx.x * blockDim.x + threadIdx.x; n < NN; n += stride) {
        int g = gid[n];
        unsafeAtomicAdd(&cnt[g], 1.f);
        #pragma unroll
        for (int j = 0; j < 5; ++j)
            unsafeAtomicAdd(&tot[g * 5 + j], h[(size_t)n * 5 + j]);
    }
}

__global__ void readout_final(const float* __restrict__ tot, const float* __restrict__ cnt,
                              float* __restrict__ out) {
    int tid = blockIdx.x * blockDim.x + threadIdx.x;
    if (tid < NG * 5) {
        int g = tid / 5;
        out[tid] = tot[tid] / fmaxf(cnt[g], 1.f);
    }
}

extern "C" void kernel_launch(void* const* d_in, const int* in_sizes, int n_in,
                              void* d_out, int out_size, void* d_ws, size_t ws_size,
                              hipStream_t stream) {
    const float* feat = (const float*)d_in[0];
    const int*   src  = (const int*)d_in[1];
    const int*   dst  = (const int*)d_in[2];
    const int*   gid  = (const int*)d_in[3];
    const float* Ws0 = (const float*)d_in[4],  *Wn0 = (const float*)d_in[5],  *b0 = (const float*)d_in[6];
    const float* Ws1 = (const float*)d_in[7],  *Wn1 = (const float*)d_in[8],  *b1 = (const float*)d_in[9];
    const float* Ws2 = (const float*)d_in[10], *Wn2 = (const float*)d_in[11], *b2 = (const float*)d_in[12];
    const float* Ws3 = (const float*)d_in[13], *Wn3 = (const float*)d_in[14], *b3 = (const float*)d_in[15];
    float* out = (float*)d_out;

    // workspace layout (floats)
    float* ws   = (float*)d_ws;
    float* inv  = ws;                           // NN
    float* bufA = inv  + NN;                    // NN*128  (h between layers)
    float* bufB = bufA + (size_t)NN * 128;      // NN*48
    float* bufC = bufB + (size_t)NN * 48;       // NN*48
    float* bufD = bufC + (size_t)NN * 48;       // NN*48
    float* tot  = bufD + (size_t)NN * 48;       // NG*5
    float* cnt  = tot  + NG * 5;                // NG

    const dim3 blk(256);
    const int NODE_GRID = 4096;
    const int EDGE_GRID = 8192;

    // ---- degree (once; reuse bufD as int scratch) ----
    hipMemsetAsync(bufD, 0, NN * sizeof(int), stream);
    deg_kernel<<<4096, blk, 0, stream>>>(dst, (int*)bufD);
    inv_kernel<<<(NN + 255) / 256, blk, 0, stream>>>((const int*)bufD, inv);

    // ---- layer 0: aggregate 32-dim input, then project to 128 ----
    hipMemsetAsync(bufD, 0, (size_t)NN * 32 * sizeof(float), stream);
    edge_agg_v4<32><<<EDGE_GRID, blk, 0, stream>>>(src, dst, feat, bufD);
    layer0_kernel<<<NODE_GRID, blk, 0, stream>>>(feat, bufD, Ws0, Wn0, b0, inv, bufA);

    // ---- layer 1: project 128->48 first, aggregate 48 ----
    proj_dual_kernel<128, 48><<<NODE_GRID, blk, 0, stream>>>(bufA, Ws1, Wn1, bufD, bufB);
    hipMemsetAsync(bufC, 0, (size_t)NN * 48 * sizeof(float), stream);
    edge_agg_v4<48><<<EDGE_GRID, blk, 0, stream>>>(src, dst, bufB, bufC);
    combine_kernel<48, true><<<NODE_GRID, blk, 0, stream>>>(bufD, bufC, b1, inv, bufA);

    // ---- layer 2: project 48->28 first, aggregate 28 ----
    proj_dual_kernel<48, 28><<<NODE_GRID, blk, 0, stream>>>(bufA, Ws2, Wn2, bufD, bufB);
    hipMemsetAsync(bufC, 0, (size_t)NN * 28 * sizeof(float), stream);
    edge_agg_v4<28><<<EDGE_GRID, blk, 0, stream>>>(src, dst, bufB, bufC);
    combine_kernel<28, true><<<NODE_GRID, blk, 0, stream>>>(bufD, bufC, b2, inv, bufA);

    // ---- layer 3: project 28->5 first, aggregate 5, no relu ----
    proj_dual_kernel<28, 5><<<NODE_GRID, blk, 0, stream>>>(bufA, Ws3, Wn3, bufD, bufB);
    hipMemsetAsync(bufC, 0, (size_t)NN * 5 * sizeof(float), stream);
    edge_agg_d5<<<EDGE_GRID, blk, 0, stream>>>(src, dst, bufB, bufC);
    combine_kernel<5, false><<<NODE_GRID, blk, 0, stream>>>(bufD, bufC, b3, inv, bufA);

    // ---- per-graph mean readout ----
    hipMemsetAsync(tot, 0, (NG * 5 + NG) * sizeof(float), stream);
    readout_acc<<<2048, blk, 0, stream>>>(bufA, gid, tot, cnt);
    readout_final<<<(NG * 5 + 255) / 256, blk, 0, stream>>>(tot, cnt, out);
}

// Round 2
// 1798.831 us; speedup vs baseline: 3.7707x; 3.7707x over previous
//
#include <hip/hip_runtime.h>

#define NN 200000
#define NE 3200000
#define NG 400
#define NB 196  // ceil(NN / 1024)

// ---------------- degree histogram ----------------
__global__ void deg_kernel(const int* __restrict__ dst, int* __restrict__ deg) {
    int stride = gridDim.x * blockDim.x;
    for (int e = blockIdx.x * blockDim.x + threadIdx.x; e < NE; e += stride)
        atomicAdd(&deg[dst[e]], 1);
}

__global__ void inv_kernel(const int* __restrict__ deg, float* __restrict__ inv) {
    int n = blockIdx.x * blockDim.x + threadIdx.x;
    if (n < NN) inv[n] = 1.0f / fmaxf((float)deg[n], 1.0f);
}

// ---------------- exclusive scan of deg -> row_ptr (3 kernels) ----------------
__global__ void chunk_sums(const int* __restrict__ deg, int* __restrict__ bsum) {
    __shared__ int red[256];
    int b = blockIdx.x, t = threadIdx.x;
    int base = b * 1024 + t;
    int s = 0;
    #pragma unroll
    for (int i = 0; i < 4; ++i) { int idx = base + i * 256; if (idx < NN) s += deg[idx]; }
    red[t] = s; __syncthreads();
    for (int off = 128; off > 0; off >>= 1) {
        if (t < off) red[t] += red[t + off];
        __syncthreads();
    }
    if (t == 0) bsum[b] = red[0];
}

__global__ void scan_bsums(int* __restrict__ bsum, int* __restrict__ row_ptr) {
    __shared__ int sh[256];
    int t = threadIdx.x;
    int own = (t < NB) ? bsum[t] : 0;
    sh[t] = own; __syncthreads();
    for (int off = 1; off < 256; off <<= 1) {
        int v = (t >= off) ? sh[t - off] : 0;
        __syncthreads();
        sh[t] += v;
        __syncthreads();
    }
    if (t < NB) bsum[t] = sh[t] - own;      // exclusive
    if (t == 0) row_ptr[NN] = NE;
}

__global__ void scan_write(const int* __restrict__ deg, const int* __restrict__ bsum,
                           int* __restrict__ row_ptr, int* __restrict__ cursor) {
    __shared__ int sh[256];
    int b = blockIdx.x, t = threadIdx.x;
    int base = b * 1024 + t * 4;
    int v0 = (base     < NN) ? deg[base]     : 0;
    int v1 = (base + 1 < NN) ? deg[base + 1] : 0;
    int v2 = (base + 2 < NN) ? deg[base + 2] : 0;
    int v3 = (base + 3 < NN) ? deg[base + 3] : 0;
    int own = v0 + v1 + v2 + v3;
    sh[t] = own; __syncthreads();
    for (int off = 1; off < 256; off <<= 1) {
        int x = (t >= off) ? sh[t - off] : 0;
        __syncthreads();
        sh[t] += x;
        __syncthreads();
    }
    int excl = sh[t] - own + bsum[b];
    if (base     < NN) { row_ptr[base]     = excl; cursor[base]     = excl; excl += v0; }
    if (base + 1 < NN) { row_ptr[base + 1] = excl; cursor[base + 1] = excl; excl += v1; }
    if (base + 2 < NN) { row_ptr[base + 2] = excl; cursor[base + 2] = excl; excl += v2; }
    if (base + 3 < NN) { row_ptr[base + 3] = excl; cursor[base + 3] = excl; }
}

__global__ void csr_scatter(const int* __restrict__ src, const int* __restrict__ dst,
                            int* __restrict__ cursor, int* __restrict__ csr_src) {
    int stride = gridDim.x * blockDim.x;
    for (int e = blockIdx.x * blockDim.x + threadIdx.x; e < NE; e += stride) {
        int p = atomicAdd(&cursor[dst[e]], 1);
        csr_src[p] = src[e];
    }
}

// ---------------- pull-gather: agg[n] = sum_{u in N(n)} x[u]  (float4 lanes) --
template<int D>
__global__ void gather_sum_v4(const int* __restrict__ rp, const int* __restrict__ cs,
                              const float* __restrict__ x, float* __restrict__ agg) {
    constexpr int Q = D / 4;
    const int total = NN * Q;
    int tid = blockIdx.x * blockDim.x + threadIdx.x;
    if (tid >= total) return;
    int n = tid / Q, q = tid - n * Q;
    int e = rp[n], end = rp[n + 1];
    float4 acc = make_float4(0.f, 0.f, 0.f, 0.f);
    for (; e + 2 <= end; e += 2) {
        int s0 = cs[e], s1 = cs[e + 1];
        float4 a = *(const float4*)(x + (size_t)s0 * D + q * 4);
        float4 b = *(const float4*)(x + (size_t)s1 * D + q * 4);
        acc.x += a.x + b.x; acc.y += a.y + b.y;
        acc.z += a.z + b.z; acc.w += a.w + b.w;
    }
    if (e < end) {
        float4 a = *(const float4*)(x + (size_t)cs[e] * D + q * 4);
        acc.x += a.x; acc.y += a.y; acc.z += a.z; acc.w += a.w;
    }
    *(float4*)(agg + (size_t)tid * 4) = acc;
}

// pull-gather fused with combine: out = act(hs + inv*sum + b)
template<int D, bool RELU>
__global__ void gather_combine_v4(const int* __restrict__ rp, const int* __restrict__ cs,
                                  const float* __restrict__ xn, const float* __restrict__ hs,
                                  const float* __restrict__ bias, const float* __restrict__ inv,
                                  float* __restrict__ out) {
    constexpr int Q = D / 4;
    const int total = NN * Q;
    int tid = blockIdx.x * blockDim.x + threadIdx.x;
    if (tid >= total) return;
    int n = tid / Q, q = tid - n * Q;
    int e = rp[n], end = rp[n + 1];
    float4 acc = make_float4(0.f, 0.f, 0.f, 0.f);
    for (; e + 2 <= end; e += 2) {
        int s0 = cs[e], s1 = cs[e + 1];
        float4 a = *(const float4*)(xn + (size_t)s0 * D + q * 4);
        float4 b = *(const float4*)(xn + (size_t)s1 * D + q * 4);
        acc.x += a.x + b.x; acc.y += a.y + b.y;
        acc.z += a.z + b.z; acc.w += a.w + b.w;
    }
    if (e < end) {
        float4 a = *(const float4*)(xn + (size_t)cs[e] * D + q * 4);
        acc.x += a.x; acc.y += a.y; acc.z += a.z; acc.w += a.w;
    }
    float iv = inv[n];
    float4 h = *(const float4*)(hs + (size_t)tid * 4);
    float4 bb = *(const float4*)(bias + q * 4);
    float4 r;
    r.x = h.x + iv * acc.x + bb.x;
    r.y = h.y + iv * acc.y + bb.y;
    r.z = h.z + iv * acc.z + bb.z;
    r.w = h.w + iv * acc.w + bb.w;
    if (RELU) {
        r.x = fmaxf(r.x, 0.f); r.y = fmaxf(r.y, 0.f);
        r.z = fmaxf(r.z, 0.f); r.w = fmaxf(r.w, 0.f);
    }
    *(float4*)(out + (size_t)tid * 4) = r;
}

// scalar variant (D=5)
template<int D, bool RELU>
__global__ void gather_combine_s(const int* __restrict__ rp, const int* __restrict__ cs,
                                 const float* __restrict__ xn, const float* __restrict__ hs,
                                 const float* __restrict__ bias, const float* __restrict__ inv,
                                 float* __restrict__ out) {
    const int total = NN * D;
    int tid = blockIdx.x * blockDim.x + threadIdx.x;
    if (tid >= total) return;
    int n = tid / D, j = tid - n * D;
    int e = rp[n], end = rp[n + 1];
    float acc = 0.f;
    for (; e + 2 <= end; e += 2) {
        int s0 = cs[e], s1 = cs[e + 1];
        acc += xn[(size_t)s0 * D + j] + xn[(size_t)s1 * D + j];
    }
    if (e < end) acc += xn[(size_t)cs[e] * D + j];
    float r = hs[tid] + inv[n] * acc + bias[j];
    out[tid] = RELU ? fmaxf(r, 0.f) : r;
}

// ---------------- layer 0: out = relu(feat@Ws + inv*(agg@Wn) + b), 32->128 --
__global__ void layer0_v4(const float* __restrict__ feat, const float* __restrict__ agg,
                          const float* __restrict__ Ws, const float* __restrict__ Wn,
                          const float* __restrict__ bias, const float* __restrict__ inv,
                          float* __restrict__ out) {
    const int total = NN * 32;   // each thread does 4 outputs
    int tid = blockIdx.x * blockDim.x + threadIdx.x;
    if (tid >= total) return;
    int n = tid >> 5, q = tid & 31;
    const float* f = feat + (size_t)n * 32;
    const float* a = agg + (size_t)n * 32;
    float4 aS = make_float4(0.f, 0.f, 0.f, 0.f);
    float4 aN = make_float4(0.f, 0.f, 0.f, 0.f);
    #pragma unroll 8
    for (int k = 0; k < 32; ++k) {
        float fv = f[k], av = a[k];
        float4 ws = *(const float4*)(Ws + k * 128 + q * 4);
        float4 wn = *(const float4*)(Wn + k * 128 + q * 4);
        aS.x = fmaf(fv, ws.x, aS.x); aS.y = fmaf(fv, ws.y, aS.y);
        aS.z = fmaf(fv, ws.z, aS.z); aS.w = fmaf(fv, ws.w, aS.w);
        aN.x = fmaf(av, wn.x, aN.x); aN.y = fmaf(av, wn.y, aN.y);
        aN.z = fmaf(av, wn.z, aN.z); aN.w = fmaf(av, wn.w, aN.w);
    }
    float iv = inv[n];
    float4 bb = *(const float4*)(bias + q * 4);
    float4 r;
    r.x = fmaxf(aS.x + iv * aN.x + bb.x, 0.f);
    r.y = fmaxf(aS.y + iv * aN.y + bb.y, 0.f);
    r.z = fmaxf(aS.z + iv * aN.z + bb.z, 0.f);
    r.w = fmaxf(aS.w + iv * aN.w + bb.w, 0.f);
    *(float4*)(out + (size_t)tid * 4) = r;
}

// ---------------- dual projection, vectorized over DOUT (DOUT%4==0) ---------
template<int DIN, int DOUT>
__global__ void proj_dual_v4(const float* __restrict__ h,
                             const float* __restrict__ Ws, const float* __restrict__ Wn,
                             float* __restrict__ hs, float* __restrict__ hn) {
    constexpr int Q = DOUT / 4;
    const int total = NN * Q;
    int tid = blockIdx.x * blockDim.x + threadIdx.x;
    if (tid >= total) return;
    int n = tid / Q, q = tid - n * Q;
    const float* r = h + (size_t)n * DIN;
    float4 aS = make_float4(0.f, 0.f, 0.f, 0.f);
    float4 aN = make_float4(0.f, 0.f, 0.f, 0.f);
    #pragma unroll 4
    for (int k = 0; k < DIN; ++k) {
        float v = r[k];
        float4 ws = *(const float4*)(Ws + k * DOUT + q * 4);
        float4 wn = *(const float4*)(Wn + k * DOUT + q * 4);
        aS.x = fmaf(v, ws.x, aS.x); aS.y = fmaf(v, ws.y, aS.y);
        aS.z = fmaf(v, ws.z, aS.z); aS.w = fmaf(v, ws.w, aS.w);
        aN.x = fmaf(v, wn.x, aN.x); aN.y = fmaf(v, wn.y, aN.y);
        aN.z = fmaf(v, wn.z, aN.z); aN.w = fmaf(v, wn.w, aN.w);
    }
    *(float4*)(hs + (size_t)tid * 4) = aS;
    *(float4*)(hn + (size_t)tid * 4) = aN;
}

// scalar dual projection (DOUT=5)
template<int DIN, int DOUT>
__global__ void proj_dual_s(const float* __restrict__ h,
                            const float* __restrict__ Ws, const float* __restrict__ Wn,
                            float* __restrict__ hs, float* __restrict__ hn) {
    const int total = NN * DOUT;
    int tid = blockIdx.x * blockDim.x + threadIdx.x;
    if (tid >= total) return;
    int n = tid / DOUT, j = tid - n * DOUT;
    const float* r = h + (size_t)n * DIN;
    float aS = 0.f, aN = 0.f;
    #pragma unroll 4
    for (int k = 0; k < DIN; ++k) {
        float v = r[k];
        aS = fmaf(v, Ws[k * DOUT + j], aS);
        aN = fmaf(v, Wn[k * DOUT + j], aN);
    }
    hs[tid] = aS;
    hn[tid] = aN;
}

// ---------------- per-graph mean readout ----------------
__global__ void readout_acc(const float* __restrict__ h, const int* __restrict__ gid,
                            float* __restrict__ tot, float* __restrict__ cnt) {
    int n = blockIdx.x * blockDim.x + threadIdx.x;
    if (n >= NN) return;
    int g = gid[n];
    unsafeAtomicAdd(&cnt[g], 1.f);
    #pragma unroll
    for (int j = 0; j < 5; ++j)
        unsafeAtomicAdd(&tot[g * 5 + j], h[(size_t)n * 5 + j]);
}

__global__ void readout_final(const float* __restrict__ tot, const float* __restrict__ cnt,
                              float* __restrict__ out) {
    int tid = blockIdx.x * blockDim.x + threadIdx.x;
    if (tid < NG * 5) {
        int g = tid / 5;
        out[tid] = tot[tid] / fmaxf(cnt[g], 1.f);
    }
}

extern "C" void kernel_launch(void* const* d_in, const int* in_sizes, int n_in,
                              void* d_out, int out_size, void* d_ws, size_t ws_size,
                              hipStream_t stream) {
    const float* feat = (const float*)d_in[0];
    const int*   src  = (const int*)d_in[1];
    const int*   dst  = (const int*)d_in[2];
    const int*   gid  = (const int*)d_in[3];
    const float* Ws0 = (const float*)d_in[4],  *Wn0 = (const float*)d_in[5],  *b0 = (const float*)d_in[6];
    const float* Ws1 = (const float*)d_in[7],  *Wn1 = (const float*)d_in[8],  *b1 = (const float*)d_in[9];
    const float* Ws2 = (const float*)d_in[10], *Wn2 = (const float*)d_in[11], *b2 = (const float*)d_in[12];
    const float* Ws3 = (const float*)d_in[13], *Wn3 = (const float*)d_in[14], *b3 = (const float*)d_in[15];
    float* out = (float*)d_out;

    // ---- workspace layout ----
    float* ws   = (float*)d_ws;
    float* inv  = ws;                            // NN
    float* bufA = inv  + NN;                     // NN*128 (h between layers)
    float* bufB = bufA + (size_t)NN * 128;       // NN*48  (agg32 / hs)
    float* bufC = bufB + (size_t)NN * 48;        // NN*48  (hn)
    float* tot  = bufC + (size_t)NN * 48;        // NG*5
    float* cnt  = tot  + NG * 5;                 // NG
    int*   deg     = (int*)(cnt + NG);           // NN
    int*   row_ptr = deg + NN;                   // NN+1
    int*   cursor  = row_ptr + NN + 1;           // NN
    int*   bsum    = cursor + NN;                // NB
    int*   csr_src = bsum + 256;                 // NE

    const dim3 blk(256);
    auto g1 = [](int total) { return dim3((total + 255) / 256); };

    // ---- CSR build (once; graph shared by all 4 layers) ----
    hipMemsetAsync(deg, 0, NN * sizeof(int), stream);
    deg_kernel<<<2048, blk, 0, stream>>>(dst, deg);
    inv_kernel<<<g1(NN), blk, 0, stream>>>(deg, inv);
    chunk_sums<<<NB, blk, 0, stream>>>(deg, bsum);
    scan_bsums<<<1, blk, 0, stream>>>(bsum, row_ptr);
    scan_write<<<NB, blk, 0, stream>>>(deg, bsum, row_ptr, cursor);
    csr_scatter<<<2048, blk, 0, stream>>>(src, dst, cursor, csr_src);

    // ---- layer 0: aggregate 32-dim input (pull), then project to 128 ----
    gather_sum_v4<32><<<g1(NN * 8), blk, 0, stream>>>(row_ptr, csr_src, feat, bufB);
    layer0_v4<<<g1(NN * 32), blk, 0, stream>>>(feat, bufB, Ws0, Wn0, b0, inv, bufA);

    // ---- layer 1: project 128->48, pull-aggregate 48, combine ----
    proj_dual_v4<128, 48><<<g1(NN * 12), blk, 0, stream>>>(bufA, Ws1, Wn1, bufB, bufC);
    gather_combine_v4<48, true><<<g1(NN * 12), blk, 0, stream>>>(row_ptr, csr_src, bufC, bufB, b1, inv, bufA);

    // ---- layer 2: project 48->28, pull-aggregate 28, combine ----
    proj_dual_v4<48, 28><<<g1(NN * 7), blk, 0, stream>>>(bufA, Ws2, Wn2, bufB, bufC);
    gather_combine_v4<28, true><<<g1(NN * 7), blk, 0, stream>>>(row_ptr, csr_src, bufC, bufB, b2, inv, bufA);

    // ---- layer 3: project 28->5, pull-aggregate 5, combine (no relu) ----
    proj_dual_s<28, 5><<<g1(NN * 5), blk, 0, stream>>>(bufA, Ws3, Wn3, bufB, bufC);
    gather_combine_s<5, false><<<g1(NN * 5), blk, 0, stream>>>(row_ptr, csr_src, bufC, bufB, b3, inv, bufA);

    // ---- per-graph mean readout ----
    hipMemsetAsync(tot, 0, (NG * 5 + NG) * sizeof(float), stream);
    readout_acc<<<g1(NN), blk, 0, stream>>>(bufA, gid, tot, cnt);
    readout_final<<<g1(NG * 5), blk, 0, stream>>>(tot, cnt, out);
}

// Round 3
// 1457.799 us; speedup vs baseline: 4.6528x; 1.2339x over previous
//
#include <hip/hip_runtime.h>

#define NN 200000
#define NE 3200000
#define NG 400
#define NB 196  // ceil(NN / 1024)

// ---------------- degree histogram ----------------
__global__ void deg_kernel(const int* __restrict__ dst, int* __restrict__ deg) {
    int stride = gridDim.x * blockDim.x;
    for (int e = blockIdx.x * blockDim.x + threadIdx.x; e < NE; e += stride)
        atomicAdd(&deg[dst[e]], 1);
}

__global__ void inv_kernel(const int* __restrict__ deg, float* __restrict__ inv) {
    int n = blockIdx.x * blockDim.x + threadIdx.x;
    if (n < NN) inv[n] = 1.0f / fmaxf((float)deg[n], 1.0f);
}

// ---------------- exclusive scan of deg -> row_ptr (3 kernels) ----------------
__global__ void chunk_sums(const int* __restrict__ deg, int* __restrict__ bsum) {
    __shared__ int red[256];
    int b = blockIdx.x, t = threadIdx.x;
    int base = b * 1024 + t;
    int s = 0;
    #pragma unroll
    for (int i = 0; i < 4; ++i) { int idx = base + i * 256; if (idx < NN) s += deg[idx]; }
    red[t] = s; __syncthreads();
    for (int off = 128; off > 0; off >>= 1) {
        if (t < off) red[t] += red[t + off];
        __syncthreads();
    }
    if (t == 0) bsum[b] = red[0];
}

__global__ void scan_bsums(int* __restrict__ bsum, int* __restrict__ row_ptr) {
    __shared__ int sh[256];
    int t = threadIdx.x;
    int own = (t < NB) ? bsum[t] : 0;
    sh[t] = own; __syncthreads();
    for (int off = 1; off < 256; off <<= 1) {
        int v = (t >= off) ? sh[t - off] : 0;
        __syncthreads();
        sh[t] += v;
        __syncthreads();
    }
    if (t < NB) bsum[t] = sh[t] - own;      // exclusive
    if (t == 0) row_ptr[NN] = NE;
}

__global__ void scan_write(const int* __restrict__ deg, const int* __restrict__ bsum,
                           int* __restrict__ row_ptr, int* __restrict__ cursor) {
    __shared__ int sh[256];
    int b = blockIdx.x, t = threadIdx.x;
    int base = b * 1024 + t * 4;
    int v0 = (base     < NN) ? deg[base]     : 0;
    int v1 = (base + 1 < NN) ? deg[base + 1] : 0;
    int v2 = (base + 2 < NN) ? deg[base + 2] : 0;
    int v3 = (base + 3 < NN) ? deg[base + 3] : 0;
    int own = v0 + v1 + v2 + v3;
    sh[t] = own; __syncthreads();
    for (int off = 1; off < 256; off <<= 1) {
        int x = (t >= off) ? sh[t - off] : 0;
        __syncthreads();
        sh[t] += x;
        __syncthreads();
    }
    int excl = sh[t] - own + bsum[b];
    if (base     < NN) { row_ptr[base]     = excl; cursor[base]     = excl; excl += v0; }
    if (base + 1 < NN) { row_ptr[base + 1] = excl; cursor[base + 1] = excl; excl += v1; }
    if (base + 2 < NN) { row_ptr[base + 2] = excl; cursor[base + 2] = excl; excl += v2; }
    if (base + 3 < NN) { row_ptr[base + 3] = excl; cursor[base + 3] = excl; }
}

__global__ void csr_scatter(const int* __restrict__ src, const int* __restrict__ dst,
                            int* __restrict__ cursor, int* __restrict__ csr_src) {
    int stride = gridDim.x * blockDim.x;
    for (int e = blockIdx.x * blockDim.x + threadIdx.x; e < NE; e += stride) {
        int p = atomicAdd(&cursor[dst[e]], 1);
        csr_src[p] = src[e];
    }
}

// ---------------- pull-gather: agg[n] = sum_{u in N(n)} x[u]  (float4 lanes) --
template<int D>
__global__ void gather_sum_v4(const int* __restrict__ rp, const int* __restrict__ cs,
                              const float* __restrict__ x, float* __restrict__ agg) {
    constexpr int Q = D / 4;
    const int total = NN * Q;
    int tid = blockIdx.x * blockDim.x + threadIdx.x;
    if (tid >= total) return;
    int n = tid / Q, q = tid - n * Q;
    int e = rp[n], end = rp[n + 1];
    float4 acc = make_float4(0.f, 0.f, 0.f, 0.f);
    for (; e + 2 <= end; e += 2) {
        int s0 = cs[e], s1 = cs[e + 1];
        float4 a = *(const float4*)(x + (size_t)s0 * D + q * 4);
        float4 b = *(const float4*)(x + (size_t)s1 * D + q * 4);
        acc.x += a.x + b.x; acc.y += a.y + b.y;
        acc.z += a.z + b.z; acc.w += a.w + b.w;
    }
    if (e < end) {
        float4 a = *(const float4*)(x + (size_t)cs[e] * D + q * 4);
        acc.x += a.x; acc.y += a.y; acc.z += a.z; acc.w += a.w;
    }
    *(float4*)(agg + (size_t)tid * 4) = acc;
}

// pull-gather fused with combine: out = act(hs + inv*sum + b)
template<int D, bool RELU>
__global__ void gather_combine_v4(const int* __restrict__ rp, const int* __restrict__ cs,
                                  const float* __restrict__ xn, const float* __restrict__ hs,
                                  const float* __restrict__ bias, const float* __restrict__ inv,
                                  float* __restrict__ out) {
    constexpr int Q = D / 4;
    const int total = NN * Q;
    int tid = blockIdx.x * blockDim.x + threadIdx.x;
    if (tid >= total) return;
    int n = tid / Q, q = tid - n * Q;
    int e = rp[n], end = rp[n + 1];
    float4 acc = make_float4(0.f, 0.f, 0.f, 0.f);
    for (; e + 2 <= end; e += 2) {
        int s0 = cs[e], s1 = cs[e + 1];
        float4 a = *(const float4*)(xn + (size_t)s0 * D + q * 4);
        float4 b = *(const float4*)(xn + (size_t)s1 * D + q * 4);
        acc.x += a.x + b.x; acc.y += a.y + b.y;
        acc.z += a.z + b.z; acc.w += a.w + b.w;
    }
    if (e < end) {
        float4 a = *(const float4*)(xn + (size_t)cs[e] * D + q * 4);
        acc.x += a.x; acc.y += a.y; acc.z += a.z; acc.w += a.w;
    }
    float iv = inv[n];
    float4 h = *(const float4*)(hs + (size_t)tid * 4);
    float4 bb = *(const float4*)(bias + q * 4);
    float4 r;
    r.x = h.x + iv * acc.x + bb.x;
    r.y = h.y + iv * acc.y + bb.y;
    r.z = h.z + iv * acc.z + bb.z;
    r.w = h.w + iv * acc.w + bb.w;
    if (RELU) {
        r.x = fmaxf(r.x, 0.f); r.y = fmaxf(r.y, 0.f);
        r.z = fmaxf(r.z, 0.f); r.w = fmaxf(r.w, 0.f);
    }
    *(float4*)(out + (size_t)tid * 4) = r;
}

// scalar variant (D=5)
template<int D, bool RELU>
__global__ void gather_combine_s(const int* __restrict__ rp, const int* __restrict__ cs,
                                 const float* __restrict__ xn, const float* __restrict__ hs,
                                 const float* __restrict__ bias, const float* __restrict__ inv,
                                 float* __restrict__ out) {
    const int total = NN * D;
    int tid = blockIdx.x * blockDim.x + threadIdx.x;
    if (tid >= total) return;
    int n = tid / D, j = tid - n * D;
    int e = rp[n], end = rp[n + 1];
    float acc = 0.f;
    for (; e + 2 <= end; e += 2) {
        int s0 = cs[e], s1 = cs[e + 1];
        acc += xn[(size_t)s0 * D + j] + xn[(size_t)s1 * D + j];
    }
    if (e < end) acc += xn[(size_t)cs[e] * D + j];
    float r = hs[tid] + inv[n] * acc + bias[j];
    out[tid] = RELU ? fmaxf(r, 0.f) : r;
}

// ---------------- layer 0: out = relu(feat@Ws + inv*(agg@Wn) + b), 32->128 --
__global__ void layer0_v4(const float* __restrict__ feat, const float* __restrict__ agg,
                          const float* __restrict__ Ws, const float* __restrict__ Wn,
                          const float* __restrict__ bias, const float* __restrict__ inv,
                          float* __restrict__ out) {
    const int total = NN * 32;   // each thread does 4 outputs
    int tid = blockIdx.x * blockDim.x + threadIdx.x;
    if (tid >= total) return;
    int n = tid >> 5, q = tid & 31;
    const float* f = feat + (size_t)n * 32;
    const float* a = agg + (size_t)n * 32;
    float4 aS = make_float4(0.f, 0.f, 0.f, 0.f);
    float4 aN = make_float4(0.f, 0.f, 0.f, 0.f);
    #pragma unroll 8
    for (int k = 0; k < 32; ++k) {
        float fv = f[k], av = a[k];
        float4 ws = *(const float4*)(Ws + k * 128 + q * 4);
        float4 wn = *(const float4*)(Wn + k * 128 + q * 4);
        aS.x = fmaf(fv, ws.x, aS.x); aS.y = fmaf(fv, ws.y, aS.y);
        aS.z = fmaf(fv, ws.z, aS.z); aS.w = fmaf(fv, ws.w, aS.w);
        aN.x = fmaf(av, wn.x, aN.x); aN.y = fmaf(av, wn.y, aN.y);
        aN.z = fmaf(av, wn.z, aN.z); aN.w = fmaf(av, wn.w, aN.w);
    }
    float iv = inv[n];
    float4 bb = *(const float4*)(bias + q * 4);
    float4 r;
    r.x = fmaxf(aS.x + iv * aN.x + bb.x, 0.f);
    r.y = fmaxf(aS.y + iv * aN.y + bb.y, 0.f);
    r.z = fmaxf(aS.z + iv * aN.z + bb.z, 0.f);
    r.w = fmaxf(aS.w + iv * aN.w + bb.w, 0.f);
    *(float4*)(out + (size_t)tid * 4) = r;
}

// ---------------- dual projection, vectorized over DOUT (DOUT%4==0) ---------
template<int DIN, int DOUT>
__global__ void proj_dual_v4(const float* __restrict__ h,
                             const float* __restrict__ Ws, const float* __restrict__ Wn,
                             float* __restrict__ hs, float* __restrict__ hn) {
    constexpr int Q = DOUT / 4;
    const int total = NN * Q;
    int tid = blockIdx.x * blockDim.x + threadIdx.x;
    if (tid >= total) return;
    int n = tid / Q, q = tid - n * Q;
    const float* r = h + (size_t)n * DIN;
    float4 aS = make_float4(0.f, 0.f, 0.f, 0.f);
    float4 aN = make_float4(0.f, 0.f, 0.f, 0.f);
    #pragma unroll 4
    for (int k = 0; k < DIN; ++k) {
        float v = r[k];
        float4 ws = *(const float4*)(Ws + k * DOUT + q * 4);
        float4 wn = *(const float4*)(Wn + k * DOUT + q * 4);
        aS.x = fmaf(v, ws.x, aS.x); aS.y = fmaf(v, ws.y, aS.y);
        aS.z = fmaf(v, ws.z, aS.z); aS.w = fmaf(v, ws.w, aS.w);
        aN.x = fmaf(v, wn.x, aN.x); aN.y = fmaf(v, wn.y, aN.y);
        aN.z = fmaf(v, wn.z, aN.z); aN.w = fmaf(v, wn.w, aN.w);
    }
    *(float4*)(hs + (size_t)tid * 4) = aS;
    *(float4*)(hn + (size_t)tid * 4) = aN;
}

// scalar dual projection (DOUT=5)
template<int DIN, int DOUT>
__global__ void proj_dual_s(const float* __restrict__ h,
                            const float* __restrict__ Ws, const float* __restrict__ Wn,
                            float* __restrict__ hs, float* __restrict__ hn) {
    const int total = NN * DOUT;
    int tid = blockIdx.x * blockDim.x + threadIdx.x;
    if (tid >= total) return;
    int n = tid / DOUT, j = tid - n * DOUT;
    const float* r = h + (size_t)n * DIN;
    float aS = 0.f, aN = 0.f;
    #pragma unroll 4
    for (int k = 0; k < DIN; ++k) {
        float v = r[k];
        aS = fmaf(v, Ws[k * DOUT + j], aS);
        aN = fmaf(v, Wn[k * DOUT + j], aN);
    }
    hs[tid] = aS;
    hn[tid] = aN;
}

// ---------------- per-graph mean readout: one block per graph ----------------
// graph_ids is sorted -> graph g owns contiguous rows [lb, ub). Binary search
// the range, block-strided register sums, LDS tree reduce, write mean. 0 atomics.
__global__ void readout_graph(const float* __restrict__ h, const int* __restrict__ gid,
                              float* __restrict__ out) {
    const int g = blockIdx.x;
    const int t = threadIdx.x;
    // lower bound: first i with gid[i] >= g
    int lo = 0, hi = NN;
    while (lo < hi) { int mid = (lo + hi) >> 1; if (gid[mid] < g) lo = mid + 1; else hi = mid; }
    const int start = lo;
    // upper bound: first i with gid[i] > g
    hi = NN;
    while (lo < hi) { int mid = (lo + hi) >> 1; if (gid[mid] <= g) lo = mid + 1; else hi = mid; }
    const int end = lo;

    float acc[5] = {0.f, 0.f, 0.f, 0.f, 0.f};
    for (int n = start + t; n < end; n += blockDim.x) {
        const float* row = h + (size_t)n * 5;
        #pragma unroll
        for (int j = 0; j < 5; ++j) acc[j] += row[j];
    }
    __shared__ float sh[5][256];
    #pragma unroll
    for (int j = 0; j < 5; ++j) sh[j][t] = acc[j];
    __syncthreads();
    for (int off = 128; off > 0; off >>= 1) {
        if (t < off) {
            #pragma unroll
            for (int j = 0; j < 5; ++j) sh[j][t] += sh[j][t + off];
        }
        __syncthreads();
    }
    if (t < 5) {
        float cnt = (float)(end - start);
        out[g * 5 + t] = sh[t][0] / fmaxf(cnt, 1.f);
    }
}

extern "C" void kernel_launch(void* const* d_in, const int* in_sizes, int n_in,
                              void* d_out, int out_size, void* d_ws, size_t ws_size,
                              hipStream_t stream) {
    const float* feat = (const float*)d_in[0];
    const int*   src  = (const int*)d_in[1];
    const int*   dst  = (const int*)d_in[2];
    const int*   gid  = (const int*)d_in[3];
    const float* Ws0 = (const float*)d_in[4],  *Wn0 = (const float*)d_in[5],  *b0 = (const float*)d_in[6];
    const float* Ws1 = (const float*)d_in[7],  *Wn1 = (const float*)d_in[8],  *b1 = (const float*)d_in[9];
    const float* Ws2 = (const float*)d_in[10], *Wn2 = (const float*)d_in[11], *b2 = (const float*)d_in[12];
    const float* Ws3 = (const float*)d_in[13], *Wn3 = (const float*)d_in[14], *b3 = (const float*)d_in[15];
    float* out = (float*)d_out;

    // ---- workspace layout ----
    float* ws   = (float*)d_ws;
    float* inv  = ws;                            // NN
    float* bufA = inv  + NN;                     // NN*128 (h between layers)
    float* bufB = bufA + (size_t)NN * 128;       // NN*48  (agg32 / hs)
    float* bufC = bufB + (size_t)NN * 48;        // NN*48  (hn)
    int*   deg     = (int*)(bufC + (size_t)NN * 48); // NN
    int*   row_ptr = deg + NN;                   // NN+1
    int*   cursor  = row_ptr + NN + 1;           // NN
    int*   bsum    = cursor + NN;                // 256
    int*   csr_src = bsum + 256;                 // NE

    const dim3 blk(256);
    auto g1 = [](int total) { return dim3((total + 255) / 256); };

    // ---- CSR build (once; graph shared by all 4 layers) ----
    hipMemsetAsync(deg, 0, NN * sizeof(int), stream);
    deg_kernel<<<2048, blk, 0, stream>>>(dst, deg);
    inv_kernel<<<g1(NN), blk, 0, stream>>>(deg, inv);
    chunk_sums<<<NB, blk, 0, stream>>>(deg, bsum);
    scan_bsums<<<1, blk, 0, stream>>>(bsum, row_ptr);
    scan_write<<<NB, blk, 0, stream>>>(deg, bsum, row_ptr, cursor);
    csr_scatter<<<2048, blk, 0, stream>>>(src, dst, cursor, csr_src);

    // ---- layer 0: aggregate 32-dim input (pull), then project to 128 ----
    gather_sum_v4<32><<<g1(NN * 8), blk, 0, stream>>>(row_ptr, csr_src, feat, bufB);
    layer0_v4<<<g1(NN * 32), blk, 0, stream>>>(feat, bufB, Ws0, Wn0, b0, inv, bufA);

    // ---- layer 1: project 128->48, pull-aggregate 48, combine ----
    proj_dual_v4<128, 48><<<g1(NN * 12), blk, 0, stream>>>(bufA, Ws1, Wn1, bufB, bufC);
    gather_combine_v4<48, true><<<g1(NN * 12), blk, 0, stream>>>(row_ptr, csr_src, bufC, bufB, b1, inv, bufA);

    // ---- layer 2: project 48->28, pull-aggregate 28, combine ----
    proj_dual_v4<48, 28><<<g1(NN * 7), blk, 0, stream>>>(bufA, Ws2, Wn2, bufB, bufC);
    gather_combine_v4<28, true><<<g1(NN * 7), blk, 0, stream>>>(row_ptr, csr_src, bufC, bufB, b2, inv, bufA);

    // ---- layer 3: project 28->5, pull-aggregate 5, combine (no relu) ----
    proj_dual_s<28, 5><<<g1(NN * 5), blk, 0, stream>>>(bufA, Ws3, Wn3, bufB, bufC);
    gather_combine_s<5, false><<<g1(NN * 5), blk, 0, stream>>>(row_ptr, csr_src, bufC, bufB, b3, inv, bufA);

    // ---- per-graph mean readout: 1 block/graph, no atomics ----
    readout_graph<<<NG, blk, 0, stream>>>(bufA, gid, out);
}

// Round 4
// 938.940 us; speedup vs baseline: 7.2240x; 1.5526x over previous
//
#include <hip/hip_runtime.h>

#define NN 200000
#define NE 3200000
#define NG 400
#define NB 196  // ceil(NN / 1024)

// ---------------- degree histogram ----------------
__global__ void deg_kernel(const int* __restrict__ dst, int* __restrict__ deg) {
    int stride = gridDim.x * blockDim.x;
    for (int e = blockIdx.x * blockDim.x + threadIdx.x; e < NE; e += stride)
        atomicAdd(&deg[dst[e]], 1);
}

__global__ void inv_kernel(const int* __restrict__ deg, float* __restrict__ inv) {
    int n = blockIdx.x * blockDim.x + threadIdx.x;
    if (n < NN) inv[n] = 1.0f / fmaxf((float)deg[n], 1.0f);
}

// ---------------- exclusive scan of deg -> row_ptr ----------------
__global__ void chunk_sums(const int* __restrict__ deg, int* __restrict__ bsum) {
    __shared__ int red[256];
    int b = blockIdx.x, t = threadIdx.x;
    int base = b * 1024 + t;
    int s = 0;
    #pragma unroll
    for (int i = 0; i < 4; ++i) { int idx = base + i * 256; if (idx < NN) s += deg[idx]; }
    red[t] = s; __syncthreads();
    for (int off = 128; off > 0; off >>= 1) {
        if (t < off) red[t] += red[t + off];
        __syncthreads();
    }
    if (t == 0) bsum[b] = red[0];
}

__global__ void scan_bsums(int* __restrict__ bsum, int* __restrict__ row_ptr) {
    __shared__ int sh[256];
    int t = threadIdx.x;
    int own = (t < NB) ? bsum[t] : 0;
    sh[t] = own; __syncthreads();
    for (int off = 1; off < 256; off <<= 1) {
        int v = (t >= off) ? sh[t - off] : 0;
        __syncthreads();
        sh[t] += v;
        __syncthreads();
    }
    if (t < NB) bsum[t] = sh[t] - own;      // exclusive
    if (t == 0) row_ptr[NN] = NE;
}

__global__ void scan_write(const int* __restrict__ deg, const int* __restrict__ bsum,
                           int* __restrict__ row_ptr, int* __restrict__ cursor) {
    __shared__ int sh[256];
    int b = blockIdx.x, t = threadIdx.x;
    int base = b * 1024 + t * 4;
    int v0 = (base     < NN) ? deg[base]     : 0;
    int v1 = (base + 1 < NN) ? deg[base + 1] : 0;
    int v2 = (base + 2 < NN) ? deg[base + 2] : 0;
    int v3 = (base + 3 < NN) ? deg[base + 3] : 0;
    int own = v0 + v1 + v2 + v3;
    sh[t] = own; __syncthreads();
    for (int off = 1; off < 256; off <<= 1) {
        int x = (t >= off) ? sh[t - off] : 0;
        __syncthreads();
        sh[t] += x;
        __syncthreads();
    }
    int excl = sh[t] - own + bsum[b];
    if (base     < NN) { row_ptr[base]     = excl; cursor[base]     = excl; excl += v0; }
    if (base + 1 < NN) { row_ptr[base + 1] = excl; cursor[base + 1] = excl; excl += v1; }
    if (base + 2 < NN) { row_ptr[base + 2] = excl; cursor[base + 2] = excl; excl += v2; }
    if (base + 3 < NN) { row_ptr[base + 3] = excl; cursor[base + 3] = excl; }
}

__global__ void csr_scatter(const int* __restrict__ src, const int* __restrict__ dst,
                            int* __restrict__ cursor, int* __restrict__ csr_src) {
    int stride = gridDim.x * blockDim.x;
    for (int e = blockIdx.x * blockDim.x + threadIdx.x; e < NE; e += stride) {
        int p = atomicAdd(&cursor[dst[e]], 1);
        csr_src[p] = src[e];
    }
}

// ================= gather with LDS-staged edge indices =================
// Block owns nodes [n0, n0+NPB): its CSR edge range is contiguous. Stage it
// into LDS once (vs Q redundant global reads). Fallback to global if > CAP.
template<int D, bool COMBINE, bool RELU>
__global__ void gather_lds_v4(const int* __restrict__ rp, const int* __restrict__ cs,
                              const float* __restrict__ xn, const float* __restrict__ hs,
                              const float* __restrict__ bias, const float* __restrict__ inv,
                              float* __restrict__ out) {
    constexpr int Q = D / 4;
    constexpr int NPB = 256 / Q;
    constexpr int CAP = 4096;
    __shared__ int shIdx[CAP];
    int n0 = blockIdx.x * NPB;
    if (n0 >= NN) return;
    int nEnd = min(n0 + NPB, NN);
    int e0 = rp[n0];
    int cnt = rp[nEnd] - e0;
    bool useLds = (cnt <= CAP);
    if (useLds)
        for (int i = threadIdx.x; i < cnt; i += 256) shIdx[i] = cs[e0 + i];
    __syncthreads();
    int t = threadIdx.x;
    int q = t % Q, l = t / Q;
    int n = n0 + l;
    if (l >= NPB || n >= NN) return;
    int s = rp[n] - e0, e = rp[n + 1] - e0;
    float4 acc = make_float4(0.f, 0.f, 0.f, 0.f);
    if (useLds) {
        int j = s;
        for (; j + 2 <= e; j += 2) {
            int s0 = shIdx[j], s1 = shIdx[j + 1];
            float4 a = *(const float4*)(xn + (size_t)s0 * D + q * 4);
            float4 b = *(const float4*)(xn + (size_t)s1 * D + q * 4);
            acc.x += a.x + b.x; acc.y += a.y + b.y;
            acc.z += a.z + b.z; acc.w += a.w + b.w;
        }
        if (j < e) {
            float4 a = *(const float4*)(xn + (size_t)shIdx[j] * D + q * 4);
            acc.x += a.x; acc.y += a.y; acc.z += a.z; acc.w += a.w;
        }
    } else {
        int j = s;
        for (; j + 2 <= e; j += 2) {
            int s0 = cs[e0 + j], s1 = cs[e0 + j + 1];
            float4 a = *(const float4*)(xn + (size_t)s0 * D + q * 4);
            float4 b = *(const float4*)(xn + (size_t)s1 * D + q * 4);
            acc.x += a.x + b.x; acc.y += a.y + b.y;
            acc.z += a.z + b.z; acc.w += a.w + b.w;
        }
        if (j < e) {
            float4 a = *(const float4*)(xn + (size_t)cs[e0 + j] * D + q * 4);
            acc.x += a.x; acc.y += a.y; acc.z += a.z; acc.w += a.w;
        }
    }
    size_t oidx = (size_t)n * D + q * 4;
    if (COMBINE) {
        float iv = inv[n];
        float4 h = *(const float4*)(hs + oidx);
        float4 bb = *(const float4*)(bias + q * 4);
        float4 r;
        r.x = h.x + iv * acc.x + bb.x;
        r.y = h.y + iv * acc.y + bb.y;
        r.z = h.z + iv * acc.z + bb.z;
        r.w = h.w + iv * acc.w + bb.w;
        if (RELU) {
            r.x = fmaxf(r.x, 0.f); r.y = fmaxf(r.y, 0.f);
            r.z = fmaxf(r.z, 0.f); r.w = fmaxf(r.w, 0.f);
        }
        *(float4*)(out + oidx) = r;
    } else {
        *(float4*)(out + oidx) = acc;
    }
}

// scalar D=5 variant with LDS-staged indices, fused combine (no relu)
__global__ void gather_lds_s5(const int* __restrict__ rp, const int* __restrict__ cs,
                              const float* __restrict__ xn, const float* __restrict__ hs,
                              const float* __restrict__ bias, const float* __restrict__ inv,
                              float* __restrict__ out) {
    constexpr int D = 5, Q = 5, NPB = 51, CAP = 4096;
    __shared__ int shIdx[CAP];
    int n0 = blockIdx.x * NPB;
    if (n0 >= NN) return;
    int nEnd = min(n0 + NPB, NN);
    int e0 = rp[n0];
    int cnt = rp[nEnd] - e0;
    bool useLds = (cnt <= CAP);
    if (useLds)
        for (int i = threadIdx.x; i < cnt; i += 256) shIdx[i] = cs[e0 + i];
    __syncthreads();
    int t = threadIdx.x;
    int q = t % Q, l = t / Q;
    int n = n0 + l;
    if (l >= NPB || n >= NN) return;
    int s = rp[n] - e0, e = rp[n + 1] - e0;
    float acc = 0.f;
    if (useLds) {
        int j = s;
        for (; j + 2 <= e; j += 2)
            acc += xn[(size_t)shIdx[j] * D + q] + xn[(size_t)shIdx[j + 1] * D + q];
        if (j < e) acc += xn[(size_t)shIdx[j] * D + q];
    } else {
        int j = s;
        for (; j + 2 <= e; j += 2)
            acc += xn[(size_t)cs[e0 + j] * D + q] + xn[(size_t)cs[e0 + j + 1] * D + q];
        if (j < e) acc += xn[(size_t)cs[e0 + j] * D + q];
    }
    size_t oidx = (size_t)n * D + q;
    out[oidx] = hs[oidx] + inv[n] * acc + bias[q];
}

// ================= LDS-staged dual GEMM: hs = h@Ws, hn = h@Wn =================
// Weights staged in LDS once per block; NPER nodes per thread so each weight
// read feeds 8*NPER FMAs. FMA-bound by construction.
template<int DIN, int DOUT, int NPER>
__global__ void proj_dual_lds(const float* __restrict__ h,
                              const float* __restrict__ Ws, const float* __restrict__ Wn,
                              float* __restrict__ hs, float* __restrict__ hn) {
    constexpr int Q = DOUT / 4;
    constexpr int GROUPS = 256 / Q;
    constexpr int NPB = GROUPS * NPER;
    __shared__ float4 shW[DIN * 2 * Q];
    const float4* Ws4 = (const float4*)Ws;
    const float4* Wn4 = (const float4*)Wn;
    for (int i = threadIdx.x; i < DIN * Q; i += 256) {
        int k = i / Q, q = i - k * Q;
        shW[k * 2 * Q + q]     = Ws4[i];
        shW[k * 2 * Q + Q + q] = Wn4[i];
    }
    __syncthreads();
    int t = threadIdx.x;
    int q = t % Q, g = t / Q;
    if (g >= GROUPS) return;
    int n0 = blockIdx.x * NPB + g * NPER;
    if (n0 >= NN) return;

    if (n0 + NPER <= NN) {
        float4 aS[NPER], aN[NPER];
        #pragma unroll
        for (int i = 0; i < NPER; ++i) {
            aS[i] = make_float4(0.f, 0.f, 0.f, 0.f);
            aN[i] = make_float4(0.f, 0.f, 0.f, 0.f);
        }
        const float* hp = h + (size_t)n0 * DIN;
        for (int kk = 0; kk < DIN; kk += 4) {
            float4 hv[NPER];
            #pragma unroll
            for (int i = 0; i < NPER; ++i)
                hv[i] = *(const float4*)(hp + (size_t)i * DIN + kk);
            #pragma unroll
            for (int dk = 0; dk < 4; ++dk) {
                float4 ws = shW[(kk + dk) * 2 * Q + q];
                float4 wn = shW[(kk + dk) * 2 * Q + Q + q];
                #pragma unroll
                for (int i = 0; i < NPER; ++i) {
                    float v = ((const float*)&hv[i])[dk];
                    aS[i].x = fmaf(v, ws.x, aS[i].x); aS[i].y = fmaf(v, ws.y, aS[i].y);
                    aS[i].z = fmaf(v, ws.z, aS[i].z); aS[i].w = fmaf(v, ws.w, aS[i].w);
                    aN[i].x = fmaf(v, wn.x, aN[i].x); aN[i].y = fmaf(v, wn.y, aN[i].y);
                    aN[i].z = fmaf(v, wn.z, aN[i].z); aN[i].w = fmaf(v, wn.w, aN[i].w);
                }
            }
        }
        #pragma unroll
        for (int i = 0; i < NPER; ++i) {
            *(float4*)(hs + (size_t)(n0 + i) * DOUT + q * 4) = aS[i];
            *(float4*)(hn + (size_t)(n0 + i) * DOUT + q * 4) = aN[i];
        }
    } else {
        // partial tail block: per-node path
        for (int i = 0; i < NPER; ++i) {
            int n = n0 + i;
            if (n >= NN) break;
            float4 aS = make_float4(0.f, 0.f, 0.f, 0.f);
            float4 aN = make_float4(0.f, 0.f, 0.f, 0.f);
            const float* hp = h + (size_t)n * DIN;
            for (int kk = 0; kk < DIN; kk += 4) {
                float4 hv = *(const float4*)(hp + kk);
                #pragma unroll
                for (int dk = 0; dk < 4; ++dk) {
                    float4 ws = shW[(kk + dk) * 2 * Q + q];
                    float4 wn = shW[(kk + dk) * 2 * Q + Q + q];
                    float v = ((const float*)&hv)[dk];
                    aS.x = fmaf(v, ws.x, aS.x); aS.y = fmaf(v, ws.y, aS.y);
                    aS.z = fmaf(v, ws.z, aS.z); aS.w = fmaf(v, ws.w, aS.w);
                    aN.x = fmaf(v, wn.x, aN.x); aN.y = fmaf(v, wn.y, aN.y);
                    aN.z = fmaf(v, wn.z, aN.z); aN.w = fmaf(v, wn.w, aN.w);
                }
            }
            *(float4*)(hs + (size_t)n * DOUT + q * 4) = aS;
            *(float4*)(hn + (size_t)n * DOUT + q * 4) = aN;
        }
    }
}

// scalar dual projection (DOUT=5) — small, keep simple
template<int DIN, int DOUT>
__global__ void proj_dual_s(const float* __restrict__ h,
                            const float* __restrict__ Ws, const float* __restrict__ Wn,
                            float* __restrict__ hs, float* __restrict__ hn) {
    const int total = NN * DOUT;
    int tid = blockIdx.x * blockDim.x + threadIdx.x;
    if (tid >= total) return;
    int n = tid / DOUT, j = tid - n * DOUT;
    const float* r = h + (size_t)n * DIN;
    float aS = 0.f, aN = 0.f;
    #pragma unroll 4
    for (int k = 0; k < DIN; ++k) {
        float v = r[k];
        aS = fmaf(v, Ws[k * DOUT + j], aS);
        aN = fmaf(v, Wn[k * DOUT + j], aN);
    }
    hs[tid] = aS;
    hn[tid] = aN;
}

// ================= layer 0 with LDS-staged weights =================
// out = relu(feat@Ws + inv*(agg@Wn) + b), 32->128
__global__ void layer0_lds(const float* __restrict__ feat, const float* __restrict__ agg,
                           const float* __restrict__ Ws, const float* __restrict__ Wn,
                           const float* __restrict__ bias, const float* __restrict__ inv,
                           float* __restrict__ out) {
    constexpr int DIN = 32, DOUT = 128, Q = 32, GROUPS = 8, NPER = 4;
    constexpr int NPB = GROUPS * NPER;  // 32 nodes/block
    __shared__ float4 shW[DIN * 2 * Q];  // 32 KiB
    const float4* Ws4 = (const float4*)Ws;
    const float4* Wn4 = (const float4*)Wn;
    for (int i = threadIdx.x; i < DIN * Q; i += 256) {
        int k = i / Q, q = i - k * Q;
        shW[k * 2 * Q + q]     = Ws4[i];
        shW[k * 2 * Q + Q + q] = Wn4[i];
    }
    __syncthreads();
    int t = threadIdx.x;
    int q = t & 31, g = t >> 5;
    int n0 = blockIdx.x * NPB + g * NPER;
    if (n0 >= NN) return;
    float4 bb = *(const float4*)(bias + q * 4);

    if (n0 + NPER <= NN) {
        float4 aS[NPER], aN[NPER];
        #pragma unroll
        for (int i = 0; i < NPER; ++i) {
            aS[i] = make_float4(0.f, 0.f, 0.f, 0.f);
            aN[i] = make_float4(0.f, 0.f, 0.f, 0.f);
        }
        const float* fp = feat + (size_t)n0 * DIN;
        const float* ap = agg + (size_t)n0 * DIN;
        for (int kk = 0; kk < DIN; kk += 4) {
            float4 fv[NPER], av[NPER];
            #pragma unroll
            for (int i = 0; i < NPER; ++i) {
                fv[i] = *(const float4*)(fp + (size_t)i * DIN + kk);
                av[i] = *(const float4*)(ap + (size_t)i * DIN + kk);
            }
            #pragma unroll
            for (int dk = 0; dk < 4; ++dk) {
                float4 ws = shW[(kk + dk) * 2 * Q + q];
                float4 wn = shW[(kk + dk) * 2 * Q + Q + q];
                #pragma unroll
                for (int i = 0; i < NPER; ++i) {
                    float f = ((const float*)&fv[i])[dk];
                    float a = ((const float*)&av[i])[dk];
                    aS[i].x = fmaf(f, ws.x, aS[i].x); aS[i].y = fmaf(f, ws.y, aS[i].y);
                    aS[i].z = fmaf(f, ws.z, aS[i].z); aS[i].w = fmaf(f, ws.w, aS[i].w);
                    aN[i].x = fmaf(a, wn.x, aN[i].x); aN[i].y = fmaf(a, wn.y, aN[i].y);
                    aN[i].z = fmaf(a, wn.z, aN[i].z); aN[i].w = fmaf(a, wn.w, aN[i].w);
                }
            }
        }
        #pragma unroll
        for (int i = 0; i < NPER; ++i) {
            float iv = inv[n0 + i];
            float4 r;
            r.x = fmaxf(aS[i].x + iv * aN[i].x + bb.x, 0.f);
            r.y = fmaxf(aS[i].y + iv * aN[i].y + bb.y, 0.f);
            r.z = fmaxf(aS[i].z + iv * aN[i].z + bb.z, 0.f);
            r.w = fmaxf(aS[i].w + iv * aN[i].w + bb.w, 0.f);
            *(float4*)(out + (size_t)(n0 + i) * DOUT + q * 4) = r;
        }
    } else {
        for (int i = 0; i < NPER; ++i) {
            int n = n0 + i;
            if (n >= NN) break;
            float4 aS = make_float4(0.f, 0.f, 0.f, 0.f);
            float4 aN = make_float4(0.f, 0.f, 0.f, 0.f);
            for (int kk = 0; kk < DIN; kk += 4) {
                float4 fv = *(const float4*)(feat + (size_t)n * DIN + kk);
                float4 av = *(const float4*)(agg + (size_t)n * DIN + kk);
                #pragma unroll
                for (int dk = 0; dk < 4; ++dk) {
                    float4 ws = shW[(kk + dk) * 2 * Q + q];
                    float4 wn = shW[(kk + dk) * 2 * Q + Q + q];
                    float f = ((const float*)&fv)[dk];
                    float a = ((const float*)&av)[dk];
                    aS.x = fmaf(f, ws.x, aS.x); aS.y = fmaf(f, ws.y, aS.y);
                    aS.z = fmaf(f, ws.z, aS.z); aS.w = fmaf(f, ws.w, aS.w);
                    aN.x = fmaf(a, wn.x, aN.x); aN.y = fmaf(a, wn.y, aN.y);
                    aN.z = fmaf(a, wn.z, aN.z); aN.w = fmaf(a, wn.w, aN.w);
                }
            }
            float iv = inv[n];
            float4 r;
            r.x = fmaxf(aS.x + iv * aN.x + bb.x, 0.f);
            r.y = fmaxf(aS.y + iv * aN.y + bb.y, 0.f);
            r.z = fmaxf(aS.z + iv * aN.z + bb.z, 0.f);
            r.w = fmaxf(aS.w + iv * aN.w + bb.w, 0.f);
            *(float4*)(out + (size_t)n * DOUT + q * 4) = r;
        }
    }
}

// ---------------- per-graph mean readout: one block per graph ----------------
__global__ void readout_graph(const float* __restrict__ h, const int* __restrict__ gid,
                              float* __restrict__ out) {
    const int g = blockIdx.x;
    const int t = threadIdx.x;
    int lo = 0, hi = NN;
    while (lo < hi) { int mid = (lo + hi) >> 1; if (gid[mid] < g) lo = mid + 1; else hi = mid; }
    const int start = lo;
    hi = NN;
    while (lo < hi) { int mid = (lo + hi) >> 1; if (gid[mid] <= g) lo = mid + 1; else hi = mid; }
    const int end = lo;

    float acc[5] = {0.f, 0.f, 0.f, 0.f, 0.f};
    for (int n = start + t; n < end; n += blockDim.x) {
        const float* row = h + (size_t)n * 5;
        #pragma unroll
        for (int j = 0; j < 5; ++j) acc[j] += row[j];
    }
    __shared__ float sh[5][256];
    #pragma unroll
    for (int j = 0; j < 5; ++j) sh[j][t] = acc[j];
    __syncthreads();
    for (int off = 128; off > 0; off >>= 1) {
        if (t < off) {
            #pragma unroll
            for (int j = 0; j < 5; ++j) sh[j][t] += sh[j][t + off];
        }
        __syncthreads();
    }
    if (t < 5) {
        float cnt = (float)(end - start);
        out[g * 5 + t] = sh[t][0] / fmaxf(cnt, 1.f);
    }
}

extern "C" void kernel_launch(void* const* d_in, const int* in_sizes, int n_in,
                              void* d_out, int out_size, void* d_ws, size_t ws_size,
                              hipStream_t stream) {
    const float* feat = (const float*)d_in[0];
    const int*   src  = (const int*)d_in[1];
    const int*   dst  = (const int*)d_in[2];
    const int*   gid  = (const int*)d_in[3];
    const float* Ws0 = (const float*)d_in[4],  *Wn0 = (const float*)d_in[5],  *b0 = (const float*)d_in[6];
    const float* Ws1 = (const float*)d_in[7],  *Wn1 = (const float*)d_in[8],  *b1 = (const float*)d_in[9];
    const float* Ws2 = (const float*)d_in[10], *Wn2 = (const float*)d_in[11], *b2 = (const float*)d_in[12];
    const float* Ws3 = (const float*)d_in[13], *Wn3 = (const float*)d_in[14], *b3 = (const float*)d_in[15];
    float* out = (float*)d_out;

    // ---- workspace layout ----
    float* ws   = (float*)d_ws;
    float* inv  = ws;                            // NN
    float* bufA = inv  + NN;                     // NN*128 (h between layers)
    float* bufB = bufA + (size_t)NN * 128;       // NN*48  (agg32 / hs)
    float* bufC = bufB + (size_t)NN * 48;        // NN*48  (hn)
    int*   deg     = (int*)(bufC + (size_t)NN * 48); // NN
    int*   row_ptr = deg + NN;                   // NN+1
    int*   cursor  = row_ptr + NN + 1;           // NN
    int*   bsum    = cursor + NN;                // 256
    int*   csr_src = bsum + 256;                 // NE

    const dim3 blk(256);
    auto g1 = [](int total) { return dim3((total + 255) / 256); };

    // ---- CSR build (once; graph shared by all 4 layers) ----
    hipMemsetAsync(deg, 0, NN * sizeof(int), stream);
    deg_kernel<<<2048, blk, 0, stream>>>(dst, deg);
    inv_kernel<<<g1(NN), blk, 0, stream>>>(deg, inv);
    chunk_sums<<<NB, blk, 0, stream>>>(deg, bsum);
    scan_bsums<<<1, blk, 0, stream>>>(bsum, row_ptr);
    scan_write<<<NB, blk, 0, stream>>>(deg, bsum, row_ptr, cursor);
    csr_scatter<<<2048, blk, 0, stream>>>(src, dst, cursor, csr_src);

    // ---- layer 0: pull-aggregate 32-dim input, LDS-GEMM to 128 ----
    gather_lds_v4<32, false, false><<<(NN + 31) / 32, blk, 0, stream>>>(
        row_ptr, csr_src, feat, nullptr, nullptr, nullptr, bufB);
    layer0_lds<<<(NN + 31) / 32, blk, 0, stream>>>(feat, bufB, Ws0, Wn0, b0, inv, bufA);

    // ---- layer 1: LDS-GEMM 128->48 (dual), gather 48, combine ----
    proj_dual_lds<128, 48, 4><<<(NN + 83) / 84, blk, 0, stream>>>(bufA, Ws1, Wn1, bufB, bufC);
    gather_lds_v4<48, true, true><<<(NN + 20) / 21, blk, 0, stream>>>(
        row_ptr, csr_src, bufC, bufB, b1, inv, bufA);

    // ---- layer 2: LDS-GEMM 48->28 (dual), gather 28, combine ----
    proj_dual_lds<48, 28, 4><<<(NN + 143) / 144, blk, 0, stream>>>(bufA, Ws2, Wn2, bufB, bufC);
    gather_lds_v4<28, true, true><<<(NN + 35) / 36, blk, 0, stream>>>(
        row_ptr, csr_src, bufC, bufB, b2, inv, bufA);

    // ---- layer 3: 28->5 (dual), gather 5, combine (no relu) ----
    proj_dual_s<28, 5><<<g1(NN * 5), blk, 0, stream>>>(bufA, Ws3, Wn3, bufB, bufC);
    gather_lds_s5<<<(NN + 50) / 51, blk, 0, stream>>>(row_ptr, csr_src, bufC, bufB, b3, inv, bufA);

    // ---- per-graph mean readout: 1 block/graph, no atomics ----
    readout_graph<<<NG, blk, 0, stream>>>(bufA, gid, out);
}

// Round 8
// 883.398 us; speedup vs baseline: 7.6782x; 1.0629x over previous
//
#include <hip/hip_runtime.h>

#define NN 200000
#define NE 3200000
#define NG 400
#define NB 196        // ceil(NN / 1024) for node scan
#define BSHIFT 8      // 256 nodes per bucket
#define NBKT 782      // ceil(NN / 256)
#define EPB 12500     // edges per partition block (256 blocks)

// ======== CSR build, bucketed ========
// Pass 1: degree atomics (fire-and-forget) + coarse bucket histogram.
__global__ void hist_deg(const int* __restrict__ dst, int* __restrict__ deg,
                         int* __restrict__ bcnt) {
    __shared__ int h[NBKT];
    for (int i = threadIdx.x; i < NBKT; i += 256) h[i] = 0;
    __syncthreads();
    int stride = gridDim.x * blockDim.x;
    for (int e = blockIdx.x * blockDim.x + threadIdx.x; e < NE; e += stride) {
        int d = dst[e];
        atomicAdd(&deg[d], 1);
        atomicAdd(&h[d >> BSHIFT], 1);
    }
    __syncthreads();
    for (int i = threadIdx.x; i < NBKT; i += 256)
        if (h[i]) atomicAdd(&bcnt[i], h[i]);
}

__global__ void inv_kernel(const int* __restrict__ deg, float* __restrict__ inv) {
    int n = blockIdx.x * blockDim.x + threadIdx.x;
    if (n < NN) inv[n] = 1.0f / fmaxf((float)deg[n], 1.0f);
}

// scan of bucket counts -> bbase (pristine) and bcur (running cursor)
__global__ void scan_bkt(const int* __restrict__ bcnt, int* __restrict__ bbase,
                         int* __restrict__ bcur) {
    __shared__ int sh[256];
    int t = threadIdx.x;
    int v[4]; int own = 0;
    #pragma unroll
    for (int i = 0; i < 4; ++i) {
        int idx = t * 4 + i;
        v[i] = (idx < NBKT) ? bcnt[idx] : 0;
        own += v[i];
    }
    sh[t] = own; __syncthreads();
    for (int off = 1; off < 256; off <<= 1) {
        int x = (t >= off) ? sh[t - off] : 0;
        __syncthreads();
        sh[t] += x;
        __syncthreads();
    }
    int excl = sh[t] - own;
    #pragma unroll
    for (int i = 0; i < 4; ++i) {
        int idx = t * 4 + i;
        if (idx < NBKT) { bbase[idx] = excl; bcur[idx] = excl; excl += v[i]; }
    }
}

// ---------------- exclusive scan of deg -> row_ptr ----------------
__global__ void chunk_sums(const int* __restrict__ deg, int* __restrict__ bsum) {
    __shared__ int red[256];
    int b = blockIdx.x, t = threadIdx.x;
    int base = b * 1024 + t;
    int s = 0;
    #pragma unroll
    for (int i = 0; i < 4; ++i) { int idx = base + i * 256; if (idx < NN) s += deg[idx]; }
    red[t] = s; __syncthreads();
    for (int off = 128; off > 0; off >>= 1) {
        if (t < off) red[t] += red[t + off];
        __syncthreads();
    }
    if (t == 0) bsum[b] = red[0];
}

__global__ void scan_bsums(int* __restrict__ bsum, int* __restrict__ row_ptr) {
    __shared__ int sh[256];
    int t = threadIdx.x;
    int own = (t < NB) ? bsum[t] : 0;
    sh[t] = own; __syncthreads();
    for (int off = 1; off < 256; off <<= 1) {
        int v = (t >= off) ? sh[t - off] : 0;
        __syncthreads();
        sh[t] += v;
        __syncthreads();
    }
    if (t < NB) bsum[t] = sh[t] - own;      // exclusive
    if (t == 0) row_ptr[NN] = NE;
}

__global__ void scan_write(const int* __restrict__ deg, const int* __restrict__ bsum,
                           int* __restrict__ row_ptr) {
    __shared__ int sh[256];
    int b = blockIdx.x, t = threadIdx.x;
    int base = b * 1024 + t * 4;
    int v0 = (base     < NN) ? deg[base]     : 0;
    int v1 = (base + 1 < NN) ? deg[base + 1] : 0;
    int v2 = (base + 2 < NN) ? deg[base + 2] : 0;
    int v3 = (base + 3 < NN) ? deg[base + 3] : 0;
    int own = v0 + v1 + v2 + v3;
    sh[t] = own; __syncthreads();
    for (int off = 1; off < 256; off <<= 1) {
        int x = (t >= off) ? sh[t - off] : 0;
        __syncthreads();
        sh[t] += x;
        __syncthreads();
    }
    int excl = sh[t] - own + bsum[b];
    if (base     < NN) { row_ptr[base]     = excl; excl += v0; }
    if (base + 1 < NN) { row_ptr[base + 1] = excl; excl += v1; }
    if (base + 2 < NN) { row_ptr[base + 2] = excl; excl += v2; }
    if (base + 3 < NN) { row_ptr[base + 3] = excl; }
}

// Pass 2: partition edges into bucket regions (block-local coalesced chunks).
__global__ void partition_pairs(const int* __restrict__ src, const int* __restrict__ dst,
                                int* __restrict__ bcur, int2* __restrict__ pairs) {
    __shared__ int h[NBKT];
    __shared__ int base[NBKT];
    int e0 = blockIdx.x * EPB;
    int e1 = min(e0 + EPB, NE);
    for (int i = threadIdx.x; i < NBKT; i += 256) h[i] = 0;
    __syncthreads();
    for (int e = e0 + threadIdx.x; e < e1; e += 256)
        atomicAdd(&h[dst[e] >> BSHIFT], 1);
    __syncthreads();
    for (int i = threadIdx.x; i < NBKT; i += 256) {
        int c = h[i];
        base[i] = c ? atomicAdd(&bcur[i], c) : 0;
        h[i] = 0;
    }
    __syncthreads();
    for (int e = e0 + threadIdx.x; e < e1; e += 256) {
        int d = dst[e];
        int bk = d >> BSHIFT;
        int off = atomicAdd(&h[bk], 1);
        pairs[base[bk] + off] = make_int2(src[e], d);
    }
}

// Pass 3: one block per bucket; LDS per-node cursors; csr writes land in a
// ~16 KB region -> full-line writebacks, no amplification, no global atomics.
__global__ void bucket_scatter(const int2* __restrict__ pairs, const int* __restrict__ bbase,
                               const int* __restrict__ bcur, const int* __restrict__ row_ptr,
                               int* __restrict__ csr_src) {
    __shared__ int cur[1 << BSHIFT];
    int bk = blockIdx.x;
    int n0 = bk << BSHIFT;
    int nend = min(n0 + (1 << BSHIFT), NN);
    if (threadIdx.x < nend - n0) cur[threadIdx.x] = row_ptr[n0 + threadIdx.x];
    __syncthreads();
    int p0 = bbase[bk], p1 = bcur[bk];   // bcur = bbase[bk] + count after partition
    for (int i = p0 + threadIdx.x; i < p1; i += 256) {
        int2 pr = pairs[i];
        int pos = atomicAdd(&cur[pr.y & ((1 << BSHIFT) - 1)], 1);
        csr_src[pos] = pr.x;
    }
}

// ================= gather with LDS-staged edge indices =================
template<int D, bool COMBINE, bool RELU>
__global__ void gather_lds_v4(const int* __restrict__ rp, const int* __restrict__ cs,
                              const float* __restrict__ xn, const float* __restrict__ hs,
                              const float* __restrict__ bias, const float* __restrict__ inv,
                              float* __restrict__ out) {
    constexpr int Q = D / 4;
    constexpr int NPB = 256 / Q;
    constexpr int CAP = 4096;
    __shared__ int shIdx[CAP];
    int n0 = blockIdx.x * NPB;
    if (n0 >= NN) return;
    int nEnd = min(n0 + NPB, NN);
    int e0 = rp[n0];
    int cnt = rp[nEnd] - e0;
    bool useLds = (cnt <= CAP);
    if (useLds)
        for (int i = threadIdx.x; i < cnt; i += 256) shIdx[i] = cs[e0 + i];
    __syncthreads();
    int t = threadIdx.x;
    int q = t % Q, l = t / Q;
    int n = n0 + l;
    if (l >= NPB || n >= NN) return;
    int s = rp[n] - e0, e = rp[n + 1] - e0;
    float4 acc = make_float4(0.f, 0.f, 0.f, 0.f);
    if (useLds) {
        int j = s;
        for (; j + 2 <= e; j += 2) {
            int s0 = shIdx[j], s1 = shIdx[j + 1];
            float4 a = *(const float4*)(xn + (size_t)s0 * D + q * 4);
            float4 b = *(const float4*)(xn + (size_t)s1 * D + q * 4);
            acc.x += a.x + b.x; acc.y += a.y + b.y;
            acc.z += a.z + b.z; acc.w += a.w + b.w;
        }
        if (j < e) {
            float4 a = *(const float4*)(xn + (size_t)shIdx[j] * D + q * 4);
            acc.x += a.x; acc.y += a.y; acc.z += a.z; acc.w += a.w;
        }
    } else {
        int j = s;
        for (; j + 2 <= e; j += 2) {
            int s0 = cs[e0 + j], s1 = cs[e0 + j + 1];
            float4 a = *(const float4*)(xn + (size_t)s0 * D + q * 4);
            float4 b = *(const float4*)(xn + (size_t)s1 * D + q * 4);
            acc.x += a.x + b.x; acc.y += a.y + b.y;
            acc.z += a.z + b.z; acc.w += a.w + b.w;
        }
        if (j < e) {
            float4 a = *(const float4*)(xn + (size_t)cs[e0 + j] * D + q * 4);
            acc.x += a.x; acc.y += a.y; acc.z += a.z; acc.w += a.w;
        }
    }
    size_t oidx = (size_t)n * D + q * 4;
    if (COMBINE) {
        float iv = inv[n];
        float4 h = *(const float4*)(hs + oidx);
        float4 bb = *(const float4*)(bias + q * 4);
        float4 r;
        r.x = h.x + iv * acc.x + bb.x;
        r.y = h.y + iv * acc.y + bb.y;
        r.z = h.z + iv * acc.z + bb.z;
        r.w = h.w + iv * acc.w + bb.w;
        if (RELU) {
            r.x = fmaxf(r.x, 0.f); r.y = fmaxf(r.y, 0.f);
            r.z = fmaxf(r.z, 0.f); r.w = fmaxf(r.w, 0.f);
        }
        *(float4*)(out + oidx) = r;
    } else {
        *(float4*)(out + oidx) = acc;
    }
}

// scalar D=5 variant with LDS-staged indices, fused combine (no relu)
__global__ void gather_lds_s5(const int* __restrict__ rp, const int* __restrict__ cs,
                              const float* __restrict__ xn, const float* __restrict__ hs,
                              const float* __restrict__ bias, const float* __restrict__ inv,
                              float* __restrict__ out) {
    constexpr int D = 5, Q = 5, NPB = 51, CAP = 4096;
    __shared__ int shIdx[CAP];
    int n0 = blockIdx.x * NPB;
    if (n0 >= NN) return;
    int nEnd = min(n0 + NPB, NN);
    int e0 = rp[n0];
    int cnt = rp[nEnd] - e0;
    bool useLds = (cnt <= CAP);
    if (useLds)
        for (int i = threadIdx.x; i < cnt; i += 256) shIdx[i] = cs[e0 + i];
    __syncthreads();
    int t = threadIdx.x;
    int q = t % Q, l = t / Q;
    int n = n0 + l;
    if (l >= NPB || n >= NN) return;
    int s = rp[n] - e0, e = rp[n + 1] - e0;
    float acc = 0.f;
    if (useLds) {
        int j = s;
        for (; j + 2 <= e; j += 2)
            acc += xn[(size_t)shIdx[j] * D + q] + xn[(size_t)shIdx[j + 1] * D + q];
        if (j < e) acc += xn[(size_t)shIdx[j] * D + q];
    } else {
        int j = s;
        for (; j + 2 <= e; j += 2)
            acc += xn[(size_t)cs[e0 + j] * D + q] + xn[(size_t)cs[e0 + j + 1] * D + q];
        if (j < e) acc += xn[(size_t)cs[e0 + j] * D + q];
    }
    size_t oidx = (size_t)n * D + q;
    out[oidx] = hs[oidx] + inv[n] * acc + bias[q];
}

// ================= LDS-staged dual GEMM =================
template<int DIN, int DOUT, int NPER>
__global__ void proj_dual_lds(const float* __restrict__ h,
                              const float* __restrict__ Ws, const float* __restrict__ Wn,
                              float* __restrict__ hs, float* __restrict__ hn) {
    constexpr int Q = DOUT / 4;
    constexpr int GROUPS = 256 / Q;
    constexpr int NPB = GROUPS * NPER;
    __shared__ float4 shW[DIN * 2 * Q];
    const float4* Ws4 = (const float4*)Ws;
    const float4* Wn4 = (const float4*)Wn;
    for (int i = threadIdx.x; i < DIN * Q; i += 256) {
        int k = i / Q, q = i - k * Q;
        shW[k * 2 * Q + q]     = Ws4[i];
        shW[k * 2 * Q + Q + q] = Wn4[i];
    }
    __syncthreads();
    int t = threadIdx.x;
    int q = t % Q, g = t / Q;
    if (g >= GROUPS) return;
    int n0 = blockIdx.x * NPB + g * NPER;
    if (n0 >= NN) return;

    if (n0 + NPER <= NN) {
        float4 aS[NPER], aN[NPER];
        #pragma unroll
        for (int i = 0; i < NPER; ++i) {
            aS[i] = make_float4(0.f, 0.f, 0.f, 0.f);
            aN[i] = make_float4(0.f, 0.f, 0.f, 0.f);
        }
        const float* hp = h + (size_t)n0 * DIN;
        for (int kk = 0; kk < DIN; kk += 4) {
            float4 hv[NPER];
            #pragma unroll
            for (int i = 0; i < NPER; ++i)
                hv[i] = *(const float4*)(hp + (size_t)i * DIN + kk);
            #pragma unroll
            for (int dk = 0; dk < 4; ++dk) {
                float4 ws = shW[(kk + dk) * 2 * Q + q];
                float4 wn = shW[(kk + dk) * 2 * Q + Q + q];
                #pragma unroll
                for (int i = 0; i < NPER; ++i) {
                    float v = ((const float*)&hv[i])[dk];
                    aS[i].x = fmaf(v, ws.x, aS[i].x); aS[i].y = fmaf(v, ws.y, aS[i].y);
                    aS[i].z = fmaf(v, ws.z, aS[i].z); aS[i].w = fmaf(v, ws.w, aS[i].w);
                    aN[i].x = fmaf(v, wn.x, aN[i].x); aN[i].y = fmaf(v, wn.y, aN[i].y);
                    aN[i].z = fmaf(v, wn.z, aN[i].z); aN[i].w = fmaf(v, wn.w, aN[i].w);
                }
            }
        }
        #pragma unroll
        for (int i = 0; i < NPER; ++i) {
            *(float4*)(hs + (size_t)(n0 + i) * DOUT + q * 4) = aS[i];
            *(float4*)(hn + (size_t)(n0 + i) * DOUT + q * 4) = aN[i];
        }
    } else {
        for (int i = 0; i < NPER; ++i) {
            int n = n0 + i;
            if (n >= NN) break;
            float4 aS = make_float4(0.f, 0.f, 0.f, 0.f);
            float4 aN = make_float4(0.f, 0.f, 0.f, 0.f);
            const float* hp = h + (size_t)n * DIN;
            for (int kk = 0; kk < DIN; kk += 4) {
                float4 hv = *(const float4*)(hp + kk);
                #pragma unroll
                for (int dk = 0; dk < 4; ++dk) {
                    float4 ws = shW[(kk + dk) * 2 * Q + q];
                    float4 wn = shW[(kk + dk) * 2 * Q + Q + q];
                    float v = ((const float*)&hv)[dk];
                    aS.x = fmaf(v, ws.x, aS.x); aS.y = fmaf(v, ws.y, aS.y);
                    aS.z = fmaf(v, ws.z, aS.z); aS.w = fmaf(v, ws.w, aS.w);
                    aN.x = fmaf(v, wn.x, aN.x); aN.y = fmaf(v, wn.y, aN.y);
                    aN.z = fmaf(v, wn.z, aN.z); aN.w = fmaf(v, wn.w, aN.w);
                }
            }
            *(float4*)(hs + (size_t)n * DOUT + q * 4) = aS;
            *(float4*)(hn + (size_t)n * DOUT + q * 4) = aN;
        }
    }
}

// scalar dual projection (DOUT=5)
template<int DIN, int DOUT>
__global__ void proj_dual_s(const float* __restrict__ h,
                            const float* __restrict__ Ws, const float* __restrict__ Wn,
                            float* __restrict__ hs, float* __restrict__ hn) {
    const int total = NN * DOUT;
    int tid = blockIdx.x * blockDim.x + threadIdx.x;
    if (tid >= total) return;
    int n = tid / DOUT, j = tid - n * DOUT;
    const float* r = h + (size_t)n * DIN;
    float aS = 0.f, aN = 0.f;
    #pragma unroll 4
    for (int k = 0; k < DIN; ++k) {
        float v = r[k];
        aS = fmaf(v, Ws[k * DOUT + j], aS);
        aN = fmaf(v, Wn[k * DOUT + j], aN);
    }
    hs[tid] = aS;
    hn[tid] = aN;
}

// ================= layer 0 with LDS-staged weights =================
__global__ void layer0_lds(const float* __restrict__ feat, const float* __restrict__ agg,
                           const float* __restrict__ Ws, const float* __restrict__ Wn,
                           const float* __restrict__ bias, const float* __restrict__ inv,
                           float* __restrict__ out) {
    constexpr int DIN = 32, DOUT = 128, Q = 32, NPER = 4;
    constexpr int NPB = 8 * NPER;  // 32 nodes/block
    __shared__ float4 shW[DIN * 2 * Q];  // 32 KiB
    const float4* Ws4 = (const float4*)Ws;
    const float4* Wn4 = (const float4*)Wn;
    for (int i = threadIdx.x; i < DIN * Q; i += 256) {
        int k = i / Q, q = i - k * Q;
        shW[k * 2 * Q + q]     = Ws4[i];
        shW[k * 2 * Q + Q + q] = Wn4[i];
    }
    __syncthreads();
    int t = threadIdx.x;
    int q = t & 31, g = t >> 5;
    int n0 = blockIdx.x * NPB + g * NPER;
    if (n0 >= NN) return;
    float4 bb = *(const float4*)(bias + q * 4);

    if (n0 + NPER <= NN) {
        float4 aS[NPER], aN[NPER];
        #pragma unroll
        for (int i = 0; i < NPER; ++i) {
            aS[i] = make_float4(0.f, 0.f, 0.f, 0.f);
            aN[i] = make_float4(0.f, 0.f, 0.f, 0.f);
        }
        const float* fp = feat + (size_t)n0 * DIN;
        const float* ap = agg + (size_t)n0 * DIN;
        for (int kk = 0; kk < DIN; kk += 4) {
            float4 fv[NPER], av[NPER];
            #pragma unroll
            for (int i = 0; i < NPER; ++i) {
                fv[i] = *(const float4*)(fp + (size_t)i * DIN + kk);
                av[i] = *(const float4*)(ap + (size_t)i * DIN + kk);
            }
            #pragma unroll
            for (int dk = 0; dk < 4; ++dk) {
                float4 ws = shW[(kk + dk) * 2 * Q + q];
                float4 wn = shW[(kk + dk) * 2 * Q + Q + q];
                #pragma unroll
                for (int i = 0; i < NPER; ++i) {
                    float f = ((const float*)&fv[i])[dk];
                    float a = ((const float*)&av[i])[dk];
                    aS[i].x = fmaf(f, ws.x, aS[i].x); aS[i].y = fmaf(f, ws.y, aS[i].y);
                    aS[i].z = fmaf(f, ws.z, aS[i].z); aS[i].w = fmaf(f, ws.w, aS[i].w);
                    aN[i].x = fmaf(a, wn.x, aN[i].x); aN[i].y = fmaf(a, wn.y, aN[i].y);
                    aN[i].z = fmaf(a, wn.z, aN[i].z); aN[i].w = fmaf(a, wn.w, aN[i].w);
                }
            }
        }
        #pragma unroll
        for (int i = 0; i < NPER; ++i) {
            float iv = inv[n0 + i];
            float4 r;
            r.x = fmaxf(aS[i].x + iv * aN[i].x + bb.x, 0.f);
            r.y = fmaxf(aS[i].y + iv * aN[i].y + bb.y, 0.f);
            r.z = fmaxf(aS[i].z + iv * aN[i].z + bb.z, 0.f);
            r.w = fmaxf(aS[i].w + iv * aN[i].w + bb.w, 0.f);
            *(float4*)(out + (size_t)(n0 + i) * DOUT + q * 4) = r;
        }
    } else {
        for (int i = 0; i < NPER; ++i) {
            int n = n0 + i;
            if (n >= NN) break;
            float4 aS = make_float4(0.f, 0.f, 0.f, 0.f);
            float4 aN = make_float4(0.f, 0.f, 0.f, 0.f);
            for (int kk = 0; kk < DIN; kk += 4) {
                float4 fv = *(const float4*)(feat + (size_t)n * DIN + kk);
                float4 av = *(const float4*)(agg + (size_t)n * DIN + kk);
                #pragma unroll
                for (int dk = 0; dk < 4; ++dk) {
                    float4 ws = shW[(kk + dk) * 2 * Q + q];
                    float4 wn = shW[(kk + dk) * 2 * Q + Q + q];
                    float f = ((const float*)&fv)[dk];
                    float a = ((const float*)&av)[dk];
                    aS.x = fmaf(f, ws.x, aS.x); aS.y = fmaf(f, ws.y, aS.y);
                    aS.z = fmaf(f, ws.z, aS.z); aS.w = fmaf(f, ws.w, aS.w);
                    aN.x = fmaf(a, wn.x, aN.x); aN.y = fmaf(a, wn.y, aN.y);
                    aN.z = fmaf(a, wn.z, aN.z); aN.w = fmaf(a, wn.w, aN.w);
                }
            }
            float iv = inv[n];
            float4 r;
            r.x = fmaxf(aS.x + iv * aN.x + bb.x, 0.f);
            r.y = fmaxf(aS.y + iv * aN.y + bb.y, 0.f);
            r.z = fmaxf(aS.z + iv * aN.z + bb.z, 0.f);
            r.w = fmaxf(aS.w + iv * aN.w + bb.w, 0.f);
            *(float4*)(out + (size_t)n * DOUT + q * 4) = r;
        }
    }
}

// ---------------- per-graph mean readout ----------------
__global__ void readout_graph(const float* __restrict__ h, const int* __restrict__ gid,
                              float* __restrict__ out) {
    const int g = blockIdx.x;
    const int t = threadIdx.x;
    int lo = 0, hi = NN;
    while (lo < hi) { int mid = (lo + hi) >> 1; if (gid[mid] < g) lo = mid + 1; else hi = mid; }
    const int start = lo;
    hi = NN;
    while (lo < hi) { int mid = (lo + hi) >> 1; if (gid[mid] <= g) lo = mid + 1; else hi = mid; }
    const int end = lo;

    float acc[5] = {0.f, 0.f, 0.f, 0.f, 0.f};
    for (int n = start + t; n < end; n += blockDim.x) {
        const float* row = h + (size_t)n * 5;
        #pragma unroll
        for (int j = 0; j < 5; ++j) acc[j] += row[j];
    }
    __shared__ float sh[5][256];
    #pragma unroll
    for (int j = 0; j < 5; ++j) sh[j][t] = acc[j];
    __syncthreads();
    for (int off = 128; off > 0; off >>= 1) {
        if (t < off) {
            #pragma unroll
            for (int j = 0; j < 5; ++j) sh[j][t] += sh[j][t + off];
        }
        __syncthreads();
    }
    if (t < 5) {
        float cnt = (float)(end - start);
        out[g * 5 + t] = sh[t][0] / fmaxf(cnt, 1.f);
    }
}

extern "C" void kernel_launch(void* const* d_in, const int* in_sizes, int n_in,
                              void* d_out, int out_size, void* d_ws, size_t ws_size,
                              hipStream_t stream) {
    const float* feat = (const float*)d_in[0];
    const int*   src  = (const int*)d_in[1];
    const int*   dst  = (const int*)d_in[2];
    const int*   gid  = (const int*)d_in[3];
    const float* Ws0 = (const float*)d_in[4],  *Wn0 = (const float*)d_in[5],  *b0 = (const float*)d_in[6];
    const float* Ws1 = (const float*)d_in[7],  *Wn1 = (const float*)d_in[8],  *b1 = (const float*)d_in[9];
    const float* Ws2 = (const float*)d_in[10], *Wn2 = (const float*)d_in[11], *b2 = (const float*)d_in[12];
    const float* Ws3 = (const float*)d_in[13], *Wn3 = (const float*)d_in[14], *b3 = (const float*)d_in[15];
    float* out = (float*)d_out;

    // ---- workspace layout ----
    float* ws   = (float*)d_ws;
    float* inv  = ws;                            // NN
    float* bufA = inv  + NN;                     // NN*128 (h between layers)
    float* bufB = bufA + (size_t)NN * 128;       // NN*48  (agg32 / hs) — pairs live here during build
    float* bufC = bufB + (size_t)NN * 48;        // NN*48  (hn)
    int*   deg     = (int*)(bufC + (size_t)NN * 48); // NN
    int*   row_ptr = deg + NN;                   // NN+1
    int*   bsum    = row_ptr + NN + 1;           // 256
    int*   bcnt    = bsum + 256;                 // NBKT
    int*   bbase   = bcnt + NBKT;                // NBKT
    int*   bcur    = bbase + NBKT;               // NBKT
    int*   csr_src = bcur + NBKT;                // NE
    int2*  pairs   = (int2*)bufB;                // NE pairs (25.6 MB <= 38.4 MB), dead after build

    const dim3 blk(256);
    auto g1 = [](int total) { return dim3((total + 255) / 256); };

    // ---- CSR build: bucketed counting sort (write-local) ----
    hipMemsetAsync(deg, 0, NN * sizeof(int), stream);
    hipMemsetAsync(bcnt, 0, NBKT * sizeof(int), stream);
    hist_deg<<<512, blk, 0, stream>>>(dst, deg, bcnt);
    inv_kernel<<<g1(NN), blk, 0, stream>>>(deg, inv);
    scan_bkt<<<1, blk, 0, stream>>>(bcnt, bbase, bcur);
    chunk_sums<<<NB, blk, 0, stream>>>(deg, bsum);
    scan_bsums<<<1, blk, 0, stream>>>(bsum, row_ptr);
    scan_write<<<NB, blk, 0, stream>>>(deg, bsum, row_ptr);
    partition_pairs<<<(NE + EPB - 1) / EPB, blk, 0, stream>>>(src, dst, bcur, pairs);
    bucket_scatter<<<NBKT, blk, 0, stream>>>(pairs, bbase, bcur, row_ptr, csr_src);

    // ---- layer 0: pull-aggregate 32-dim input, LDS-GEMM to 128 ----
    gather_lds_v4<32, false, false><<<(NN + 31) / 32, blk, 0, stream>>>(
        row_ptr, csr_src, feat, nullptr, nullptr, nullptr, bufB);
    layer0_lds<<<(NN + 31) / 32, blk, 0, stream>>>(feat, bufB, Ws0, Wn0, b0, inv, bufA);

    // ---- layer 1: LDS-GEMM 128->48 (dual), gather 48, combine ----
    proj_dual_lds<128, 48, 4><<<(NN + 83) / 84, blk, 0, stream>>>(bufA, Ws1, Wn1, bufB, bufC);
    gather_lds_v4<48, true, true><<<(NN + 20) / 21, blk, 0, stream>>>(
        row_ptr, csr_src, bufC, bufB, b1, inv, bufA);

    // ---- layer 2: LDS-GEMM 48->28 (dual), gather 28, combine ----
    proj_dual_lds<48, 28, 4><<<(NN + 143) / 144, blk, 0, stream>>>(bufA, Ws2, Wn2, bufB, bufC);
    gather_lds_v4<28, true, true><<<(NN + 35) / 36, blk, 0, stream>>>(
        row_ptr, csr_src, bufC, bufB, b2, inv, bufA);

    // ---- layer 3: 28->5 (dual), gather 5, combine (no relu) ----
    proj_dual_s<28, 5><<<g1(NN * 5), blk, 0, stream>>>(bufA, Ws3, Wn3, bufB, bufC);
    gather_lds_s5<<<(NN + 50) / 51, blk, 0, stream>>>(row_ptr, csr_src, bufC, bufB, b3, inv, bufA);

    // ---- per-graph mean readout: 1 block/graph, no atomics ----
    readout_graph<<<NG, blk, 0, stream>>>(bufA, gid, out);
}

// Round 9
// 769.949 us; speedup vs baseline: 8.8095x; 1.1473x over previous
//
#include <hip/hip_runtime.h>

#define NN 200000
#define NE 3200000
#define NG 400
#define NB 196        // ceil(NN / 1024) for node scan
#define BSHIFT 8      // 256 nodes per bucket
#define NBKT 782      // ceil(NN / 256)
#define EPB 12500     // edges per partition block (256 blocks)
#define SRCMASK 0x3FFFF   // 18 bits: NN=200000 < 262144

// ======== CSR build, bucketed, packed ========
// Pass 1: coarse bucket histogram only (no per-node atomics).
__global__ void hist_bkt(const int* __restrict__ dst, int* __restrict__ bcnt) {
    __shared__ int h[NBKT];
    for (int i = threadIdx.x; i < NBKT; i += 256) h[i] = 0;
    __syncthreads();
    int stride = gridDim.x * blockDim.x;
    for (int e = blockIdx.x * blockDim.x + threadIdx.x; e < NE; e += stride)
        atomicAdd(&h[dst[e] >> BSHIFT], 1);
    __syncthreads();
    for (int i = threadIdx.x; i < NBKT; i += 256)
        if (h[i]) atomicAdd(&bcnt[i], h[i]);
}

// scan of bucket counts -> bbase (pristine) and bcur (running cursor)
__global__ void scan_bkt(const int* __restrict__ bcnt, int* __restrict__ bbase,
                         int* __restrict__ bcur) {
    __shared__ int sh[256];
    int t = threadIdx.x;
    int v[4]; int own = 0;
    #pragma unroll
    for (int i = 0; i < 4; ++i) {
        int idx = t * 4 + i;
        v[i] = (idx < NBKT) ? bcnt[idx] : 0;
        own += v[i];
    }
    sh[t] = own; __syncthreads();
    for (int off = 1; off < 256; off <<= 1) {
        int x = (t >= off) ? sh[t - off] : 0;
        __syncthreads();
        sh[t] += x;
        __syncthreads();
    }
    int excl = sh[t] - own;
    #pragma unroll
    for (int i = 0; i < 4; ++i) {
        int idx = t * 4 + i;
        if (idx < NBKT) { bbase[idx] = excl; bcur[idx] = excl; excl += v[i]; }
    }
}

// Pass 2: partition edges into bucket regions; PACKED (ldst<<18)|src.
__global__ void partition_pairs(const int* __restrict__ src, const int* __restrict__ dst,
                                int* __restrict__ bcur, unsigned int* __restrict__ pairs) {
    __shared__ int h[NBKT];
    __shared__ int base[NBKT];
    int e0 = blockIdx.x * EPB;
    int e1 = min(e0 + EPB, NE);
    for (int i = threadIdx.x; i < NBKT; i += 256) h[i] = 0;
    __syncthreads();
    for (int e = e0 + threadIdx.x; e < e1; e += 256)
        atomicAdd(&h[dst[e] >> BSHIFT], 1);
    __syncthreads();
    for (int i = threadIdx.x; i < NBKT; i += 256) {
        int c = h[i];
        base[i] = c ? atomicAdd(&bcur[i], c) : 0;
        h[i] = 0;
    }
    __syncthreads();
    for (int e = e0 + threadIdx.x; e < e1; e += 256) {
        int d = dst[e];
        int bk = d >> BSHIFT;
        int off = atomicAdd(&h[bk], 1);
        pairs[base[bk] + off] =
            ((unsigned int)(d & ((1 << BSHIFT) - 1)) << 18) | (unsigned int)src[e];
    }
}

// Pass 2b: per-bucket degree via LDS histogram; contiguous deg+inv writes.
__global__ void bucket_deg(const unsigned int* __restrict__ pairs,
                           const int* __restrict__ bbase, const int* __restrict__ bcur,
                           int* __restrict__ deg, float* __restrict__ inv) {
    __shared__ int h[1 << BSHIFT];
    int bk = blockIdx.x;
    h[threadIdx.x] = 0;
    __syncthreads();
    int p0 = bbase[bk], p1 = bcur[bk];
    for (int i = p0 + threadIdx.x; i < p1; i += 256)
        atomicAdd(&h[pairs[i] >> 18], 1);
    __syncthreads();
    int n = (bk << BSHIFT) + threadIdx.x;
    if (n < NN) {
        int d = h[threadIdx.x];
        deg[n] = d;
        inv[n] = 1.0f / fmaxf((float)d, 1.0f);
    }
}

// ---------------- exclusive scan of deg -> row_ptr ----------------
__global__ void chunk_sums(const int* __restrict__ deg, int* __restrict__ bsum) {
    __shared__ int red[256];
    int b = blockIdx.x, t = threadIdx.x;
    int base = b * 1024 + t;
    int s = 0;
    #pragma unroll
    for (int i = 0; i < 4; ++i) { int idx = base + i * 256; if (idx < NN) s += deg[idx]; }
    red[t] = s; __syncthreads();
    for (int off = 128; off > 0; off >>= 1) {
        if (t < off) red[t] += red[t + off];
        __syncthreads();
    }
    if (t == 0) bsum[b] = red[0];
}

__global__ void scan_bsums(int* __restrict__ bsum, int* __restrict__ row_ptr) {
    __shared__ int sh[256];
    int t = threadIdx.x;
    int own = (t < NB) ? bsum[t] : 0;
    sh[t] = own; __syncthreads();
    for (int off = 1; off < 256; off <<= 1) {
        int v = (t >= off) ? sh[t - off] : 0;
        __syncthreads();
        sh[t] += v;
        __syncthreads();
    }
    if (t < NB) bsum[t] = sh[t] - own;      // exclusive
    if (t == 0) row_ptr[NN] = NE;
}

__global__ void scan_write(const int* __restrict__ deg, const int* __restrict__ bsum,
                           int* __restrict__ row_ptr) {
    __shared__ int sh[256];
    int b = blockIdx.x, t = threadIdx.x;
    int base = b * 1024 + t * 4;
    int v0 = (base     < NN) ? deg[base]     : 0;
    int v1 = (base + 1 < NN) ? deg[base + 1] : 0;
    int v2 = (base + 2 < NN) ? deg[base + 2] : 0;
    int v3 = (base + 3 < NN) ? deg[base + 3] : 0;
    int own = v0 + v1 + v2 + v3;
    sh[t] = own; __syncthreads();
    for (int off = 1; off < 256; off <<= 1) {
        int x = (t >= off) ? sh[t - off] : 0;
        __syncthreads();
        sh[t] += x;
        __syncthreads();
    }
    int excl = sh[t] - own + bsum[b];
    if (base     < NN) { row_ptr[base]     = excl; excl += v0; }
    if (base + 1 < NN) { row_ptr[base + 1] = excl; excl += v1; }
    if (base + 2 < NN) { row_ptr[base + 2] = excl; excl += v2; }
    if (base + 3 < NN) { row_ptr[base + 3] = excl; }
}

// Pass 3: one block per bucket; LDS per-node cursors; packed pairs.
__global__ void bucket_scatter(const unsigned int* __restrict__ pairs,
                               const int* __restrict__ bbase, const int* __restrict__ bcur,
                               const int* __restrict__ row_ptr, int* __restrict__ csr_src) {
    __shared__ int cur[1 << BSHIFT];
    int bk = blockIdx.x;
    int n0 = bk << BSHIFT;
    int nend = min(n0 + (1 << BSHIFT), NN);
    if (threadIdx.x < nend - n0) cur[threadIdx.x] = row_ptr[n0 + threadIdx.x];
    __syncthreads();
    int p0 = bbase[bk], p1 = bcur[bk];
    for (int i = p0 + threadIdx.x; i < p1; i += 256) {
        unsigned int pr = pairs[i];
        int pos = atomicAdd(&cur[pr >> 18], 1);
        csr_src[pos] = (int)(pr & SRCMASK);
    }
}

// ================= gather with LDS-staged edge indices =================
template<int D, bool COMBINE, bool RELU>
__global__ void gather_lds_v4(const int* __restrict__ rp, const int* __restrict__ cs,
                              const float* __restrict__ xn, const float* __restrict__ hs,
                              const float* __restrict__ bias, const float* __restrict__ inv,
                              float* __restrict__ out) {
    constexpr int Q = D / 4;
    constexpr int NPB = 256 / Q;
    constexpr int CAP = 4096;
    __shared__ int shIdx[CAP];
    int n0 = blockIdx.x * NPB;
    if (n0 >= NN) return;
    int nEnd = min(n0 + NPB, NN);
    int e0 = rp[n0];
    int cnt = rp[nEnd] - e0;
    bool useLds = (cnt <= CAP);
    if (useLds)
        for (int i = threadIdx.x; i < cnt; i += 256) shIdx[i] = cs[e0 + i];
    __syncthreads();
    int t = threadIdx.x;
    int q = t % Q, l = t / Q;
    int n = n0 + l;
    if (l >= NPB || n >= NN) return;
    int s = rp[n] - e0, e = rp[n + 1] - e0;
    float4 acc = make_float4(0.f, 0.f, 0.f, 0.f);
    if (useLds) {
        int j = s;
        for (; j + 2 <= e; j += 2) {
            int s0 = shIdx[j], s1 = shIdx[j + 1];
            float4 a = *(const float4*)(xn + (size_t)s0 * D + q * 4);
            float4 b = *(const float4*)(xn + (size_t)s1 * D + q * 4);
            acc.x += a.x + b.x; acc.y += a.y + b.y;
            acc.z += a.z + b.z; acc.w += a.w + b.w;
        }
        if (j < e) {
            float4 a = *(const float4*)(xn + (size_t)shIdx[j] * D + q * 4);
            acc.x += a.x; acc.y += a.y; acc.z += a.z; acc.w += a.w;
        }
    } else {
        int j = s;
        for (; j + 2 <= e; j += 2) {
            int s0 = cs[e0 + j], s1 = cs[e0 + j + 1];
            float4 a = *(const float4*)(xn + (size_t)s0 * D + q * 4);
            float4 b = *(const float4*)(xn + (size_t)s1 * D + q * 4);
            acc.x += a.x + b.x; acc.y += a.y + b.y;
            acc.z += a.z + b.z; acc.w += a.w + b.w;
        }
        if (j < e) {
            float4 a = *(const float4*)(xn + (size_t)cs[e0 + j] * D + q * 4);
            acc.x += a.x; acc.y += a.y; acc.z += a.z; acc.w += a.w;
        }
    }
    size_t oidx = (size_t)n * D + q * 4;
    if (COMBINE) {
        float iv = inv[n];
        float4 h = *(const float4*)(hs + oidx);
        float4 bb = *(const float4*)(bias + q * 4);
        float4 r;
        r.x = h.x + iv * acc.x + bb.x;
        r.y = h.y + iv * acc.y + bb.y;
        r.z = h.z + iv * acc.z + bb.z;
        r.w = h.w + iv * acc.w + bb.w;
        if (RELU) {
            r.x = fmaxf(r.x, 0.f); r.y = fmaxf(r.y, 0.f);
            r.z = fmaxf(r.z, 0.f); r.w = fmaxf(r.w, 0.f);
        }
        *(float4*)(out + oidx) = r;
    } else {
        *(float4*)(out + oidx) = acc;
    }
}

// scalar D=5 variant with LDS-staged indices, fused combine (no relu)
__global__ void gather_lds_s5(const int* __restrict__ rp, const int* __restrict__ cs,
                              const float* __restrict__ xn, const float* __restrict__ hs,
                              const float* __restrict__ bias, const float* __restrict__ inv,
                              float* __restrict__ out) {
    constexpr int D = 5, Q = 5, NPB = 51, CAP = 4096;
    __shared__ int shIdx[CAP];
    int n0 = blockIdx.x * NPB;
    if (n0 >= NN) return;
    int nEnd = min(n0 + NPB, NN);
    int e0 = rp[n0];
    int cnt = rp[nEnd] - e0;
    bool useLds = (cnt <= CAP);
    if (useLds)
        for (int i = threadIdx.x; i < cnt; i += 256) shIdx[i] = cs[e0 + i];
    __syncthreads();
    int t = threadIdx.x;
    int q = t % Q, l = t / Q;
    int n = n0 + l;
    if (l >= NPB || n >= NN) return;
    int s = rp[n] - e0, e = rp[n + 1] - e0;
    float acc = 0.f;
    if (useLds) {
        int j = s;
        for (; j + 2 <= e; j += 2)
            acc += xn[(size_t)shIdx[j] * D + q] + xn[(size_t)shIdx[j + 1] * D + q];
        if (j < e) acc += xn[(size_t)shIdx[j] * D + q];
    } else {
        int j = s;
        for (; j + 2 <= e; j += 2)
            acc += xn[(size_t)cs[e0 + j] * D + q] + xn[(size_t)cs[e0 + j + 1] * D + q];
        if (j < e) acc += xn[(size_t)cs[e0 + j] * D + q];
    }
    size_t oidx = (size_t)n * D + q;
    out[oidx] = hs[oidx] + inv[n] * acc + bias[q];
}

// ================= LDS-staged dual GEMM =================
template<int DIN, int DOUT, int NPER>
__global__ void proj_dual_lds(const float* __restrict__ h,
                              const float* __restrict__ Ws, const float* __restrict__ Wn,
                              float* __restrict__ hs, float* __restrict__ hn) {
    constexpr int Q = DOUT / 4;
    constexpr int GROUPS = 256 / Q;
    constexpr int NPB = GROUPS * NPER;
    __shared__ float4 shW[DIN * 2 * Q];
    const float4* Ws4 = (const float4*)Ws;
    const float4* Wn4 = (const float4*)Wn;
    for (int i = threadIdx.x; i < DIN * Q; i += 256) {
        int k = i / Q, q = i - k * Q;
        shW[k * 2 * Q + q]     = Ws4[i];
        shW[k * 2 * Q + Q + q] = Wn4[i];
    }
    __syncthreads();
    int t = threadIdx.x;
    int q = t % Q, g = t / Q;
    if (g >= GROUPS) return;
    int n0 = blockIdx.x * NPB + g * NPER;
    if (n0 >= NN) return;

    if (n0 + NPER <= NN) {
        float4 aS[NPER], aN[NPER];
        #pragma unroll
        for (int i = 0; i < NPER; ++i) {
            aS[i] = make_float4(0.f, 0.f, 0.f, 0.f);
            aN[i] = make_float4(0.f, 0.f, 0.f, 0.f);
        }
        const float* hp = h + (size_t)n0 * DIN;
        for (int kk = 0; kk < DIN; kk += 4) {
            float4 hv[NPER];
            #pragma unroll
            for (int i = 0; i < NPER; ++i)
                hv[i] = *(const float4*)(hp + (size_t)i * DIN + kk);
            #pragma unroll
            for (int dk = 0; dk < 4; ++dk) {
                float4 ws = shW[(kk + dk) * 2 * Q + q];
                float4 wn = shW[(kk + dk) * 2 * Q + Q + q];
                #pragma unroll
                for (int i = 0; i < NPER; ++i) {
                    float v = ((const float*)&hv[i])[dk];
                    aS[i].x = fmaf(v, ws.x, aS[i].x); aS[i].y = fmaf(v, ws.y, aS[i].y);
                    aS[i].z = fmaf(v, ws.z, aS[i].z); aS[i].w = fmaf(v, ws.w, aS[i].w);
                    aN[i].x = fmaf(v, wn.x, aN[i].x); aN[i].y = fmaf(v, wn.y, aN[i].y);
                    aN[i].z = fmaf(v, wn.z, aN[i].z); aN[i].w = fmaf(v, wn.w, aN[i].w);
                }
            }
        }
        #pragma unroll
        for (int i = 0; i < NPER; ++i) {
            *(float4*)(hs + (size_t)(n0 + i) * DOUT + q * 4) = aS[i];
            *(float4*)(hn + (size_t)(n0 + i) * DOUT + q * 4) = aN[i];
        }
    } else {
        for (int i = 0; i < NPER; ++i) {
            int n = n0 + i;
            if (n >= NN) break;
            float4 aS = make_float4(0.f, 0.f, 0.f, 0.f);
            float4 aN = make_float4(0.f, 0.f, 0.f, 0.f);
            const float* hp = h + (size_t)n * DIN;
            for (int kk = 0; kk < DIN; kk += 4) {
                float4 hv = *(const float4*)(hp + kk);
                #pragma unroll
                for (int dk = 0; dk < 4; ++dk) {
                    float4 ws = shW[(kk + dk) * 2 * Q + q];
                    float4 wn = shW[(kk + dk) * 2 * Q + Q + q];
                    float v = ((const float*)&hv)[dk];
                    aS.x = fmaf(v, ws.x, aS.x); aS.y = fmaf(v, ws.y, aS.y);
                    aS.z = fmaf(v, ws.z, aS.z); aS.w = fmaf(v, ws.w, aS.w);
                    aN.x = fmaf(v, wn.x, aN.x); aN.y = fmaf(v, wn.y, aN.y);
                    aN.z = fmaf(v, wn.z, aN.z); aN.w = fmaf(v, wn.w, aN.w);
                }
            }
            *(float4*)(hs + (size_t)n * DOUT + q * 4) = aS;
            *(float4*)(hn + (size_t)n * DOUT + q * 4) = aN;
        }
    }
}

// scalar dual projection (DOUT=5)
template<int DIN, int DOUT>
__global__ void proj_dual_s(const float* __restrict__ h,
                            const float* __restrict__ Ws, const float* __restrict__ Wn,
                            float* __restrict__ hs, float* __restrict__ hn) {
    const int total = NN * DOUT;
    int tid = blockIdx.x * blockDim.x + threadIdx.x;
    if (tid >= total) return;
    int n = tid / DOUT, j = tid - n * DOUT;
    const float* r = h + (size_t)n * DIN;
    float aS = 0.f, aN = 0.f;
    #pragma unroll 4
    for (int k = 0; k < DIN; ++k) {
        float v = r[k];
        aS = fmaf(v, Ws[k * DOUT + j], aS);
        aN = fmaf(v, Wn[k * DOUT + j], aN);
    }
    hs[tid] = aS;
    hn[tid] = aN;
}

// ================= layer 0 with LDS-staged weights =================
__global__ void layer0_lds(const float* __restrict__ feat, const float* __restrict__ agg,
                           const float* __restrict__ Ws, const float* __restrict__ Wn,
                           const float* __restrict__ bias, const float* __restrict__ inv,
                           float* __restrict__ out) {
    constexpr int DIN = 32, DOUT = 128, Q = 32, NPER = 4;
    constexpr int NPB = 8 * NPER;  // 32 nodes/block
    __shared__ float4 shW[DIN * 2 * Q];  // 32 KiB
    const float4* Ws4 = (const float4*)Ws;
    const float4* Wn4 = (const float4*)Wn;
    for (int i = threadIdx.x; i < DIN * Q; i += 256) {
        int k = i / Q, q = i - k * Q;
        shW[k * 2 * Q + q]     = Ws4[i];
        shW[k * 2 * Q + Q + q] = Wn4[i];
    }
    __syncthreads();
    int t = threadIdx.x;
    int q = t & 31, g = t >> 5;
    int n0 = blockIdx.x * NPB + g * NPER;
    if (n0 >= NN) return;
    float4 bb = *(const float4*)(bias + q * 4);

    if (n0 + NPER <= NN) {
        float4 aS[NPER], aN[NPER];
        #pragma unroll
        for (int i = 0; i < NPER; ++i) {
            aS[i] = make_float4(0.f, 0.f, 0.f, 0.f);
            aN[i] = make_float4(0.f, 0.f, 0.f, 0.f);
        }
        const float* fp = feat + (size_t)n0 * DIN;
        const float* ap = agg + (size_t)n0 * DIN;
        for (int kk = 0; kk < DIN; kk += 4) {
            float4 fv[NPER], av[NPER];
            #pragma unroll
            for (int i = 0; i < NPER; ++i) {
                fv[i] = *(const float4*)(fp + (size_t)i * DIN + kk);
                av[i] = *(const float4*)(ap + (size_t)i * DIN + kk);
            }
            #pragma unroll
            for (int dk = 0; dk < 4; ++dk) {
                float4 ws = shW[(kk + dk) * 2 * Q + q];
                float4 wn = shW[(kk + dk) * 2 * Q + Q + q];
                #pragma unroll
                for (int i = 0; i < NPER; ++i) {
                    float f = ((const float*)&fv[i])[dk];
                    float a = ((const float*)&av[i])[dk];
                    aS[i].x = fmaf(f, ws.x, aS[i].x); aS[i].y = fmaf(f, ws.y, aS[i].y);
                    aS[i].z = fmaf(f, ws.z, aS[i].z); aS[i].w = fmaf(f, ws.w, aS[i].w);
                    aN[i].x = fmaf(a, wn.x, aN[i].x); aN[i].y = fmaf(a, wn.y, aN[i].y);
                    aN[i].z = fmaf(a, wn.z, aN[i].z); aN[i].w = fmaf(a, wn.w, aN[i].w);
                }
            }
        }
        #pragma unroll
        for (int i = 0; i < NPER; ++i) {
            float iv = inv[n0 + i];
            float4 r;
            r.x = fmaxf(aS[i].x + iv * aN[i].x + bb.x, 0.f);
            r.y = fmaxf(aS[i].y + iv * aN[i].y + bb.y, 0.f);
            r.z = fmaxf(aS[i].z + iv * aN[i].z + bb.z, 0.f);
            r.w = fmaxf(aS[i].w + iv * aN[i].w + bb.w, 0.f);
            *(float4*)(out + (size_t)(n0 + i) * DOUT + q * 4) = r;
        }
    } else {
        for (int i = 0; i < NPER; ++i) {
            int n = n0 + i;
            if (n >= NN) break;
            float4 aS = make_float4(0.f, 0.f, 0.f, 0.f);
            float4 aN = make_float4(0.f, 0.f, 0.f, 0.f);
            for (int kk = 0; kk < DIN; kk += 4) {
                float4 fv = *(const float4*)(feat + (size_t)n * DIN + kk);
                float4 av = *(const float4*)(agg + (size_t)n * DIN + kk);
                #pragma unroll
                for (int dk = 0; dk < 4; ++dk) {
                    float4 ws = shW[(kk + dk) * 2 * Q + q];
                    float4 wn = shW[(kk + dk) * 2 * Q + Q + q];
                    float f = ((const float*)&fv)[dk];
                    float a = ((const float*)&av)[dk];
                    aS.x = fmaf(f, ws.x, aS.x); aS.y = fmaf(f, ws.y, aS.y);
                    aS.z = fmaf(f, ws.z, aS.z); aS.w = fmaf(f, ws.w, aS.w);
                    aN.x = fmaf(a, wn.x, aN.x); aN.y = fmaf(a, wn.y, aN.y);
                    aN.z = fmaf(a, wn.z, aN.z); aN.w = fmaf(a, wn.w, aN.w);
                }
            }
            float iv = inv[n];
            float4 r;
            r.x = fmaxf(aS.x + iv * aN.x + bb.x, 0.f);
            r.y = fmaxf(aS.y + iv * aN.y + bb.y, 0.f);
            r.z = fmaxf(aS.z + iv * aN.z + bb.z, 0.f);
            r.w = fmaxf(aS.w + iv * aN.w + bb.w, 0.f);
            *(float4*)(out + (size_t)n * DOUT + q * 4) = r;
        }
    }
}

// ---------------- per-graph mean readout ----------------
__global__ void readout_graph(const float* __restrict__ h, const int* __restrict__ gid,
                              float* __restrict__ out) {
    const int g = blockIdx.x;
    const int t = threadIdx.x;
    int lo = 0, hi = NN;
    while (lo < hi) { int mid = (lo + hi) >> 1; if (gid[mid] < g) lo = mid + 1; else hi = mid; }
    const int start = lo;
    hi = NN;
    while (lo < hi) { int mid = (lo + hi) >> 1; if (gid[mid] <= g) lo = mid + 1; else hi = mid; }
    const int end = lo;

    float acc[5] = {0.f, 0.f, 0.f, 0.f, 0.f};
    for (int n = start + t; n < end; n += blockDim.x) {
        const float* row = h + (size_t)n * 5;
        #pragma unroll
        for (int j = 0; j < 5; ++j) acc[j] += row[j];
    }
    __shared__ float sh[5][256];
    #pragma unroll
    for (int j = 0; j < 5; ++j) sh[j][t] = acc[j];
    __syncthreads();
    for (int off = 128; off > 0; off >>= 1) {
        if (t < off) {
            #pragma unroll
            for (int j = 0; j < 5; ++j) sh[j][t] += sh[j][t + off];
        }
        __syncthreads();
    }
    if (t < 5) {
        float cnt = (float)(end - start);
        out[g * 5 + t] = sh[t][0] / fmaxf(cnt, 1.f);
    }
}

extern "C" void kernel_launch(void* const* d_in, const int* in_sizes, int n_in,
                              void* d_out, int out_size, void* d_ws, size_t ws_size,
                              hipStream_t stream) {
    const float* feat = (const float*)d_in[0];
    const int*   src  = (const int*)d_in[1];
    const int*   dst  = (const int*)d_in[2];
    const int*   gid  = (const int*)d_in[3];
    const float* Ws0 = (const float*)d_in[4],  *Wn0 = (const float*)d_in[5],  *b0 = (const float*)d_in[6];
    const float* Ws1 = (const float*)d_in[7],  *Wn1 = (const float*)d_in[8],  *b1 = (const float*)d_in[9];
    const float* Ws2 = (const float*)d_in[10], *Wn2 = (const float*)d_in[11], *b2 = (const float*)d_in[12];
    const float* Ws3 = (const float*)d_in[13], *Wn3 = (const float*)d_in[14], *b3 = (const float*)d_in[15];
    float* out = (float*)d_out;

    // ---- workspace layout ----
    float* ws   = (float*)d_ws;
    float* inv  = ws;                            // NN
    float* bufA = inv  + NN;                     // NN*128 (h between layers)
    float* bufB = bufA + (size_t)NN * 128;       // NN*48  (agg32 / hs) — pairs live here during build
    float* bufC = bufB + (size_t)NN * 48;        // NN*48  (hn)
    int*   deg     = (int*)(bufC + (size_t)NN * 48); // NN
    int*   row_ptr = deg + NN;                   // NN+1
    int*   bsum    = row_ptr + NN + 1;           // 256
    int*   bcnt    = bsum + 256;                 // NBKT
    int*   bbase   = bcnt + NBKT;                // NBKT
    int*   bcur    = bbase + NBKT;               // NBKT
    int*   csr_src = bcur + NBKT;                // NE
    unsigned int* pairs = (unsigned int*)bufB;   // NE packed (12.8 MB), dead after build

    const dim3 blk(256);

    // ---- CSR build: bucketed counting sort, packed, no per-node global atomics ----
    hipMemsetAsync(bcnt, 0, NBKT * sizeof(int), stream);
    hist_bkt<<<512, blk, 0, stream>>>(dst, bcnt);
    scan_bkt<<<1, blk, 0, stream>>>(bcnt, bbase, bcur);
    partition_pairs<<<(NE + EPB - 1) / EPB, blk, 0, stream>>>(src, dst, bcur, pairs);
    bucket_deg<<<NBKT, blk, 0, stream>>>(pairs, bbase, bcur, deg, inv);
    chunk_sums<<<NB, blk, 0, stream>>>(deg, bsum);
    scan_bsums<<<1, blk, 0, stream>>>(bsum, row_ptr);
    scan_write<<<NB, blk, 0, stream>>>(deg, bsum, row_ptr);
    bucket_scatter<<<NBKT, blk, 0, stream>>>(pairs, bbase, bcur, row_ptr, csr_src);

    // ---- layer 0: pull-aggregate 32-dim input, LDS-GEMM to 128 ----
    gather_lds_v4<32, false, false><<<(NN + 31) / 32, blk, 0, stream>>>(
        row_ptr, csr_src, feat, nullptr, nullptr, nullptr, bufB);
    layer0_lds<<<(NN + 31) / 32, blk, 0, stream>>>(feat, bufB, Ws0, Wn0, b0, inv, bufA);

    // ---- layer 1: LDS-GEMM 128->48 (dual), gather 48, combine ----
    proj_dual_lds<128, 48, 4><<<(NN + 83) / 84, blk, 0, stream>>>(bufA, Ws1, Wn1, bufB, bufC);
    gather_lds_v4<48, true, true><<<(NN + 20) / 21, blk, 0, stream>>>(
        row_ptr, csr_src, bufC, bufB, b1, inv, bufA);

    // ---- layer 2: LDS-GEMM 48->28 (dual), gather 28, combine ----
    proj_dual_lds<48, 28, 4><<<(NN + 143) / 144, blk, 0, stream>>>(bufA, Ws2, Wn2, bufB, bufC);
    gather_lds_v4<28, true, true><<<(NN + 35) / 36, blk, 0, stream>>>(
        row_ptr, csr_src, bufC, bufB, b2, inv, bufA);

    // ---- layer 3: 28->5 (dual), gather 5, combine (no relu) ----
    proj_dual_s<28, 5><<<(NN * 5 + 255) / 256, blk, 0, stream>>>(bufA, Ws3, Wn3, bufB, bufC);
    gather_lds_s5<<<(NN + 50) / 51, blk, 0, stream>>>(row_ptr, csr_src, bufC, bufB, b3, inv, bufA);

    // ---- per-graph mean readout: 1 block/graph, no atomics ----
    readout_graph<<<NG, blk, 0, stream>>>(bufA, gid, out);
}

// Round 10
// 685.825 us; speedup vs baseline: 9.8901x; 1.1227x over previous
//
#include <hip/hip_runtime.h>

#define NN 200000
#define NE 3200000
#define NG 400
#define NB 196        // ceil(NN / 1024) for node scan
#define BSHIFT 8      // 256 nodes per bucket
#define NBKT 782      // ceil(NN / 256)
#define EPB 12500     // edges per partition block (256 blocks)
#define SRCMASK 0x3FFFF   // 18 bits: NN=200000 < 262144

typedef _Float16 half_t;

// ======== CSR build, bucketed, packed (unchanged from R9) ========
__global__ void hist_bkt(const int* __restrict__ dst, int* __restrict__ bcnt) {
    __shared__ int h[NBKT];
    for (int i = threadIdx.x; i < NBKT; i += 256) h[i] = 0;
    __syncthreads();
    int stride = gridDim.x * blockDim.x;
    for (int e = blockIdx.x * blockDim.x + threadIdx.x; e < NE; e += stride)
        atomicAdd(&h[dst[e] >> BSHIFT], 1);
    __syncthreads();
    for (int i = threadIdx.x; i < NBKT; i += 256)
        if (h[i]) atomicAdd(&bcnt[i], h[i]);
}

__global__ void scan_bkt(const int* __restrict__ bcnt, int* __restrict__ bbase,
                         int* __restrict__ bcur) {
    __shared__ int sh[256];
    int t = threadIdx.x;
    int v[4]; int own = 0;
    #pragma unroll
    for (int i = 0; i < 4; ++i) {
        int idx = t * 4 + i;
        v[i] = (idx < NBKT) ? bcnt[idx] : 0;
        own += v[i];
    }
    sh[t] = own; __syncthreads();
    for (int off = 1; off < 256; off <<= 1) {
        int x = (t >= off) ? sh[t - off] : 0;
        __syncthreads();
        sh[t] += x;
        __syncthreads();
    }
    int excl = sh[t] - own;
    #pragma unroll
    for (int i = 0; i < 4; ++i) {
        int idx = t * 4 + i;
        if (idx < NBKT) { bbase[idx] = excl; bcur[idx] = excl; excl += v[i]; }
    }
}

__global__ void partition_pairs(const int* __restrict__ src, const int* __restrict__ dst,
                                int* __restrict__ bcur, unsigned int* __restrict__ pairs) {
    __shared__ int h[NBKT];
    __shared__ int base[NBKT];
    int e0 = blockIdx.x * EPB;
    int e1 = min(e0 + EPB, NE);
    for (int i = threadIdx.x; i < NBKT; i += 256) h[i] = 0;
    __syncthreads();
    for (int e = e0 + threadIdx.x; e < e1; e += 256)
        atomicAdd(&h[dst[e] >> BSHIFT], 1);
    __syncthreads();
    for (int i = threadIdx.x; i < NBKT; i += 256) {
        int c = h[i];
        base[i] = c ? atomicAdd(&bcur[i], c) : 0;
        h[i] = 0;
    }
    __syncthreads();
    for (int e = e0 + threadIdx.x; e < e1; e += 256) {
        int d = dst[e];
        int bk = d >> BSHIFT;
        int off = atomicAdd(&h[bk], 1);
        pairs[base[bk] + off] =
            ((unsigned int)(d & ((1 << BSHIFT) - 1)) << 18) | (unsigned int)src[e];
    }
}

__global__ void bucket_deg(const unsigned int* __restrict__ pairs,
                           const int* __restrict__ bbase, const int* __restrict__ bcur,
                           int* __restrict__ deg, float* __restrict__ inv) {
    __shared__ int h[1 << BSHIFT];
    int bk = blockIdx.x;
    h[threadIdx.x] = 0;
    __syncthreads();
    int p0 = bbase[bk], p1 = bcur[bk];
    for (int i = p0 + threadIdx.x; i < p1; i += 256)
        atomicAdd(&h[pairs[i] >> 18], 1);
    __syncthreads();
    int n = (bk << BSHIFT) + threadIdx.x;
    if (n < NN) {
        int d = h[threadIdx.x];
        deg[n] = d;
        inv[n] = 1.0f / fmaxf((float)d, 1.0f);
    }
}

__global__ void chunk_sums(const int* __restrict__ deg, int* __restrict__ bsum) {
    __shared__ int red[256];
    int b = blockIdx.x, t = threadIdx.x;
    int base = b * 1024 + t;
    int s = 0;
    #pragma unroll
    for (int i = 0; i < 4; ++i) { int idx = base + i * 256; if (idx < NN) s += deg[idx]; }
    red[t] = s; __syncthreads();
    for (int off = 128; off > 0; off >>= 1) {
        if (t < off) red[t] += red[t + off];
        __syncthreads();
    }
    if (t == 0) bsum[b] = red[0];
}

__global__ void scan_bsums(int* __restrict__ bsum, int* __restrict__ row_ptr) {
    __shared__ int sh[256];
    int t = threadIdx.x;
    int own = (t < NB) ? bsum[t] : 0;
    sh[t] = own; __syncthreads();
    for (int off = 1; off < 256; off <<= 1) {
        int v = (t >= off) ? sh[t - off] : 0;
        __syncthreads();
        sh[t] += v;
        __syncthreads();
    }
    if (t < NB) bsum[t] = sh[t] - own;
    if (t == 0) row_ptr[NN] = NE;
}

__global__ void scan_write(const int* __restrict__ deg, const int* __restrict__ bsum,
                           int* __restrict__ row_ptr) {
    __shared__ int sh[256];
    int b = blockIdx.x, t = threadIdx.x;
    int base = b * 1024 + t * 4;
    int v0 = (base     < NN) ? deg[base]     : 0;
    int v1 = (base + 1 < NN) ? deg[base + 1] : 0;
    int v2 = (base + 2 < NN) ? deg[base + 2] : 0;
    int v3 = (base + 3 < NN) ? deg[base + 3] : 0;
    int own = v0 + v1 + v2 + v3;
    sh[t] = own; __syncthreads();
    for (int off = 1; off < 256; off <<= 1) {
        int x = (t >= off) ? sh[t - off] : 0;
        __syncthreads();
        sh[t] += x;
        __syncthreads();
    }
    int excl = sh[t] - own + bsum[b];
    if (base     < NN) { row_ptr[base]     = excl; excl += v0; }
    if (base + 1 < NN) { row_ptr[base + 1] = excl; excl += v1; }
    if (base + 2 < NN) { row_ptr[base + 2] = excl; excl += v2; }
    if (base + 3 < NN) { row_ptr[base + 3] = excl; }
}

__global__ void bucket_scatter(const unsigned int* __restrict__ pairs,
                               const int* __restrict__ bbase, const int* __restrict__ bcur,
                               const int* __restrict__ row_ptr, int* __restrict__ csr_src) {
    __shared__ int cur[1 << BSHIFT];
    int bk = blockIdx.x;
    int n0 = bk << BSHIFT;
    int nend = min(n0 + (1 << BSHIFT), NN);
    if (threadIdx.x < nend - n0) cur[threadIdx.x] = row_ptr[n0 + threadIdx.x];
    __syncthreads();
    int p0 = bbase[bk], p1 = bcur[bk];
    for (int i = p0 + threadIdx.x; i < p1; i += 256) {
        unsigned int pr = pairs[i];
        int pos = atomicAdd(&cur[pr >> 18], 1);
        csr_src[pos] = (int)(pr & SRCMASK);
    }
}

// ================= f32 -> fp16 conversion (8 elems/thread) =================
__global__ void f32_to_h8(const float* __restrict__ in, half_t* __restrict__ out, int total8) {
    int tid = blockIdx.x * blockDim.x + threadIdx.x;
    if (tid >= total8) return;
    const float4 a = ((const float4*)in)[tid * 2];
    const float4 b = ((const float4*)in)[tid * 2 + 1];
    union { uint4 u; half_t h[8]; } r;
    r.h[0] = (half_t)a.x; r.h[1] = (half_t)a.y; r.h[2] = (half_t)a.z; r.h[3] = (half_t)a.w;
    r.h[4] = (half_t)b.x; r.h[5] = (half_t)b.y; r.h[6] = (half_t)b.z; r.h[7] = (half_t)b.w;
    ((uint4*)out)[tid] = r.u;
}

// ================= fp16 pull-gather, LDS-staged edge indices =================
// DH: halves per row (row stride). Q threads/node, each owns 8 dims.
// MODE 0: write f32 agg (stride DH). MODE 1: combine+relu, full DH real dims.
// MODE 2: combine+relu, 28 real dims (DH=32, dims 28..31 are zero pads).
template<int DH, int Q, int MODE>
__global__ void gather_h(const int* __restrict__ rp, const int* __restrict__ cs,
                         const half_t* __restrict__ xn, const float* __restrict__ hs,
                         const float* __restrict__ bias, const float* __restrict__ inv,
                         float* __restrict__ out) {
    constexpr int NPB = 256 / Q;
    constexpr int CAP = 4096;
    __shared__ int shIdx[CAP];
    int n0 = blockIdx.x * NPB;
    if (n0 >= NN) return;
    int nEnd = min(n0 + NPB, NN);
    int e0 = rp[n0];
    int cnt = rp[nEnd] - e0;
    bool useLds = (cnt <= CAP);
    if (useLds)
        for (int i = threadIdx.x; i < cnt; i += 256) shIdx[i] = cs[e0 + i];
    __syncthreads();
    int t = threadIdx.x;
    int q = t % Q, l = t / Q;
    int n = n0 + l;
    if (l >= NPB || n >= NN) return;
    int s = rp[n] - e0, e = rp[n + 1] - e0;
    float acc[8] = {0.f, 0.f, 0.f, 0.f, 0.f, 0.f, 0.f, 0.f};
    union H8 { uint4 u; half_t h[8]; };
    if (useLds) {
        int j = s;
        for (; j + 2 <= e; j += 2) {
            H8 a, b;
            a.u = *(const uint4*)(xn + (size_t)shIdx[j]     * DH + q * 8);
            b.u = *(const uint4*)(xn + (size_t)shIdx[j + 1] * DH + q * 8);
            #pragma unroll
            for (int k = 0; k < 8; ++k) acc[k] += (float)a.h[k] + (float)b.h[k];
        }
        if (j < e) {
            H8 a; a.u = *(const uint4*)(xn + (size_t)shIdx[j] * DH + q * 8);
            #pragma unroll
            for (int k = 0; k < 8; ++k) acc[k] += (float)a.h[k];
        }
    } else {
        int j = s;
        for (; j + 2 <= e; j += 2) {
            H8 a, b;
            a.u = *(const uint4*)(xn + (size_t)cs[e0 + j]     * DH + q * 8);
            b.u = *(const uint4*)(xn + (size_t)cs[e0 + j + 1] * DH + q * 8);
            #pragma unroll
            for (int k = 0; k < 8; ++k) acc[k] += (float)a.h[k] + (float)b.h[k];
        }
        if (j < e) {
            H8 a; a.u = *(const uint4*)(xn + (size_t)cs[e0 + j] * DH + q * 8);
            #pragma unroll
            for (int k = 0; k < 8; ++k) acc[k] += (float)a.h[k];
        }
    }
    size_t base = (size_t)n * DH + q * 8;
    if (MODE == 0) {
        float4 r0 = make_float4(acc[0], acc[1], acc[2], acc[3]);
        float4 r1 = make_float4(acc[4], acc[5], acc[6], acc[7]);
        *(float4*)(out + base)     = r0;
        *(float4*)(out + base + 4) = r1;
    } else {
        float iv = inv[n];
        float4 h0 = *(const float4*)(hs + base);
        float4 b0 = *(const float4*)(bias + q * 8);
        float4 r0;
        r0.x = fmaxf(h0.x + iv * acc[0] + b0.x, 0.f);
        r0.y = fmaxf(h0.y + iv * acc[1] + b0.y, 0.f);
        r0.z = fmaxf(h0.z + iv * acc[2] + b0.z, 0.f);
        r0.w = fmaxf(h0.w + iv * acc[3] + b0.w, 0.f);
        *(float4*)(out + base) = r0;
        if (MODE == 1 || q < Q - 1) {
            float4 h1 = *(const float4*)(hs + base + 4);
            float4 b1 = *(const float4*)(bias + q * 8 + 4);
            float4 r1;
            r1.x = fmaxf(h1.x + iv * acc[4] + b1.x, 0.f);
            r1.y = fmaxf(h1.y + iv * acc[5] + b1.y, 0.f);
            r1.z = fmaxf(h1.z + iv * acc[6] + b1.z, 0.f);
            r1.w = fmaxf(h1.w + iv * acc[7] + b1.w, 0.f);
            *(float4*)(out + base + 4) = r1;
        }
    }
}

// scalar D=5 gather (f32), fused combine no relu (unchanged)
__global__ void gather_lds_s5(const int* __restrict__ rp, const int* __restrict__ cs,
                              const float* __restrict__ xn, const float* __restrict__ hs,
                              const float* __restrict__ bias, const float* __restrict__ inv,
                              float* __restrict__ out) {
    constexpr int D = 5, Q = 5, NPB = 51, CAP = 4096;
    __shared__ int shIdx[CAP];
    int n0 = blockIdx.x * NPB;
    if (n0 >= NN) return;
    int nEnd = min(n0 + NPB, NN);
    int e0 = rp[n0];
    int cnt = rp[nEnd] - e0;
    bool useLds = (cnt <= CAP);
    if (useLds)
        for (int i = threadIdx.x; i < cnt; i += 256) shIdx[i] = cs[e0 + i];
    __syncthreads();
    int t = threadIdx.x;
    int q = t % Q, l = t / Q;
    int n = n0 + l;
    if (l >= NPB || n >= NN) return;
    int s = rp[n] - e0, e = rp[n + 1] - e0;
    float acc = 0.f;
    if (useLds) {
        int j = s;
        for (; j + 2 <= e; j += 2)
            acc += xn[(size_t)shIdx[j] * D + q] + xn[(size_t)shIdx[j + 1] * D + q];
        if (j < e) acc += xn[(size_t)shIdx[j] * D + q];
    } else {
        int j = s;
        for (; j + 2 <= e; j += 2)
            acc += xn[(size_t)cs[e0 + j] * D + q] + xn[(size_t)cs[e0 + j + 1] * D + q];
        if (j < e) acc += xn[(size_t)cs[e0 + j] * D + q];
    }
    size_t oidx = (size_t)n * D + q;
    out[oidx] = hs[oidx] + inv[n] * acc + bias[q];
}

// ====== LDS-staged dual GEMM: hs = h@Ws (f32, stride DOUTS), hn = h@Wn (fp16, stride DOUTS) ======
// DINS: input row stride; DOUTS >= DOUT: output row stride (pads zeroed in hn).
template<int DIN, int DINS, int DOUT, int DOUTS, int NPER>
__global__ void proj_dual_lds_h(const float* __restrict__ h,
                                const float* __restrict__ Ws, const float* __restrict__ Wn,
                                float* __restrict__ hs, half_t* __restrict__ hn) {
    constexpr int Q = DOUT / 4;
    constexpr int GROUPS = 256 / Q;
    constexpr int NPB = GROUPS * NPER;
    __shared__ float4 shW[DIN * 2 * Q];
    const float4* Ws4 = (const float4*)Ws;
    const float4* Wn4 = (const float4*)Wn;
    for (int i = threadIdx.x; i < DIN * Q; i += 256) {
        int k = i / Q, q = i - k * Q;
        shW[k * 2 * Q + q]     = Ws4[i];
        shW[k * 2 * Q + Q + q] = Wn4[i];
    }
    __syncthreads();
    int t = threadIdx.x;
    int q = t % Q, g = t / Q;
    if (g >= GROUPS) return;
    int n0 = blockIdx.x * NPB + g * NPER;
    if (n0 >= NN) return;
    union H4 { unsigned long long u; half_t hh[4]; };

    auto emit = [&](int n, const float4& aS, const float4& aN) {
        *(float4*)(hs + (size_t)n * DOUTS + q * 4) = aS;
        H4 r;
        r.hh[0] = (half_t)aN.x; r.hh[1] = (half_t)aN.y;
        r.hh[2] = (half_t)aN.z; r.hh[3] = (half_t)aN.w;
        *(unsigned long long*)(hn + (size_t)n * DOUTS + q * 4) = r.u;
        if (DOUTS > DOUT && q == Q - 1) {
            H4 z; z.u = 0ull;
            *(unsigned long long*)(hn + (size_t)n * DOUTS + DOUT) = z.u;
        }
    };

    if (n0 + NPER <= NN) {
        float4 aS[NPER], aN[NPER];
        #pragma unroll
        for (int i = 0; i < NPER; ++i) {
            aS[i] = make_float4(0.f, 0.f, 0.f, 0.f);
            aN[i] = make_float4(0.f, 0.f, 0.f, 0.f);
        }
        const float* hp = h + (size_t)n0 * DINS;
        for (int kk = 0; kk < DIN; kk += 4) {
            float4 hv[NPER];
            #pragma unroll
            for (int i = 0; i < NPER; ++i)
                hv[i] = *(const float4*)(hp + (size_t)i * DINS + kk);
            #pragma unroll
            for (int dk = 0; dk < 4; ++dk) {
                float4 ws = shW[(kk + dk) * 2 * Q + q];
                float4 wn = shW[(kk + dk) * 2 * Q + Q + q];
                #pragma unroll
                for (int i = 0; i < NPER; ++i) {
                    float v = ((const float*)&hv[i])[dk];
                    aS[i].x = fmaf(v, ws.x, aS[i].x); aS[i].y = fmaf(v, ws.y, aS[i].y);
                    aS[i].z = fmaf(v, ws.z, aS[i].z); aS[i].w = fmaf(v, ws.w, aS[i].w);
                    aN[i].x = fmaf(v, wn.x, aN[i].x); aN[i].y = fmaf(v, wn.y, aN[i].y);
                    aN[i].z = fmaf(v, wn.z, aN[i].z); aN[i].w = fmaf(v, wn.w, aN[i].w);
                }
            }
        }
        #pragma unroll
        for (int i = 0; i < NPER; ++i) emit(n0 + i, aS[i], aN[i]);
    } else {
        for (int i = 0; i < NPER; ++i) {
            int n = n0 + i;
            if (n >= NN) break;
            float4 aS = make_float4(0.f, 0.f, 0.f, 0.f);
            float4 aN = make_float4(0.f, 0.f, 0.f, 0.f);
            const float* hp = h + (size_t)n * DINS;
            for (int kk = 0; kk < DIN; kk += 4) {
                float4 hv = *(const float4*)(hp + kk);
                #pragma unroll
                for (int dk = 0; dk < 4; ++dk) {
                    float4 ws = shW[(kk + dk) * 2 * Q + q];
                    float4 wn = shW[(kk + dk) * 2 * Q + Q + q];
                    float v = ((const float*)&hv)[dk];
                    aS.x = fmaf(v, ws.x, aS.x); aS.y = fmaf(v, ws.y, aS.y);
                    aS.z = fmaf(v, ws.z, aS.z); aS.w = fmaf(v, ws.w, aS.w);
                    aN.x = fmaf(v, wn.x, aN.x); aN.y = fmaf(v, wn.y, aN.y);
                    aN.z = fmaf(v, wn.z, aN.z); aN.w = fmaf(v, wn.w, aN.w);
                }
            }
            emit(n, aS, aN);
        }
    }
}

// scalar dual projection, f32 outputs (DOUT=5); DINS = input row stride
template<int DINS, int DIN, int DOUT>
__global__ void proj_dual_s(const float* __restrict__ h,
                            const float* __restrict__ Ws, const float* __restrict__ Wn,
                            float* __restrict__ hs, float* __restrict__ hn) {
    const int total = NN * DOUT;
    int tid = blockIdx.x * blockDim.x + threadIdx.x;
    if (tid >= total) return;
    int n = tid / DOUT, j = tid - n * DOUT;
    const float* r = h + (size_t)n * DINS;
    float aS = 0.f, aN = 0.f;
    #pragma unroll 4
    for (int k = 0; k < DIN; ++k) {
        float v = r[k];
        aS = fmaf(v, Ws[k * DOUT + j], aS);
        aN = fmaf(v, Wn[k * DOUT + j], aN);
    }
    hs[tid] = aS;
    hn[tid] = aN;
}

// ================= layer 0 with LDS-staged weights (f32 agg input) =================
__global__ void layer0_lds(const float* __restrict__ feat, const float* __restrict__ agg,
                           const float* __restrict__ Ws, const float* __restrict__ Wn,
                           const float* __restrict__ bias, const float* __restrict__ inv,
                           float* __restrict__ out) {
    constexpr int DIN = 32, DOUT = 128, Q = 32, NPER = 4;
    constexpr int NPB = 8 * NPER;
    __shared__ float4 shW[DIN * 2 * Q];
    const float4* Ws4 = (const float4*)Ws;
    const float4* Wn4 = (const float4*)Wn;
    for (int i = threadIdx.x; i < DIN * Q; i += 256) {
        int k = i / Q, q = i - k * Q;
        shW[k * 2 * Q + q]     = Ws4[i];
        shW[k * 2 * Q + Q + q] = Wn4[i];
    }
    __syncthreads();
    int t = threadIdx.x;
    int q = t & 31, g = t >> 5;
    int n0 = blockIdx.x * NPB + g * NPER;
    if (n0 >= NN) return;
    float4 bb = *(const float4*)(bias + q * 4);

    if (n0 + NPER <= NN) {
        float4 aS[NPER], aN[NPER];
        #pragma unroll
        for (int i = 0; i < NPER; ++i) {
            aS[i] = make_float4(0.f, 0.f, 0.f, 0.f);
            aN[i] = make_float4(0.f, 0.f, 0.f, 0.f);
        }
        const float* fp = feat + (size_t)n0 * DIN;
        const float* ap = agg + (size_t)n0 * DIN;
        for (int kk = 0; kk < DIN; kk += 4) {
            float4 fv[NPER], av[NPER];
            #pragma unroll
            for (int i = 0; i < NPER; ++i) {
                fv[i] = *(const float4*)(fp + (size_t)i * DIN + kk);
                av[i] = *(const float4*)(ap + (size_t)i * DIN + kk);
            }
            #pragma unroll
            for (int dk = 0; dk < 4; ++dk) {
                float4 ws = shW[(kk + dk) * 2 * Q + q];
                float4 wn = shW[(kk + dk) * 2 * Q + Q + q];
                #pragma unroll
                for (int i = 0; i < NPER; ++i) {
                    float f = ((const float*)&fv[i])[dk];
                    float a = ((const float*)&av[i])[dk];
                    aS[i].x = fmaf(f, ws.x, aS[i].x); aS[i].y = fmaf(f, ws.y, aS[i].y);
                    aS[i].z = fmaf(f, ws.z, aS[i].z); aS[i].w = fmaf(f, ws.w, aS[i].w);
                    aN[i].x = fmaf(a, wn.x, aN[i].x); aN[i].y = fmaf(a, wn.y, aN[i].y);
                    aN[i].z = fmaf(a, wn.z, aN[i].z); aN[i].w = fmaf(a, wn.w, aN[i].w);
                }
            }
        }
        #pragma unroll
        for (int i = 0; i < NPER; ++i) {
            float iv = inv[n0 + i];
            float4 r;
            r.x = fmaxf(aS[i].x + iv * aN[i].x + bb.x, 0.f);
            r.y = fmaxf(aS[i].y + iv * aN[i].y + bb.y, 0.f);
            r.z = fmaxf(aS[i].z + iv * aN[i].z + bb.z, 0.f);
            r.w = fmaxf(aS[i].w + iv * aN[i].w + bb.w, 0.f);
            *(float4*)(out + (size_t)(n0 + i) * DOUT + q * 4) = r;
        }
    } else {
        for (int i = 0; i < NPER; ++i) {
            int n = n0 + i;
            if (n >= NN) break;
            float4 aS = make_float4(0.f, 0.f, 0.f, 0.f);
            float4 aN = make_float4(0.f, 0.f, 0.f, 0.f);
            for (int kk = 0; kk < DIN; kk += 4) {
                float4 fv = *(const float4*)(feat + (size_t)n * DIN + kk);
                float4 av = *(const float4*)(agg + (size_t)n * DIN + kk);
                #pragma unroll
                for (int dk = 0; dk < 4; ++dk) {
                    float4 ws = shW[(kk + dk) * 2 * Q + q];
                    float4 wn = shW[(kk + dk) * 2 * Q + Q + q];
                    float f = ((const float*)&fv)[dk];
                    float a = ((const float*)&av)[dk];
                    aS.x = fmaf(f, ws.x, aS.x); aS.y = fmaf(f, ws.y, aS.y);
                    aS.z = fmaf(f, ws.z, aS.z); aS.w = fmaf(f, ws.w, aS.w);
                    aN.x = fmaf(a, wn.x, aN.x); aN.y = fmaf(a, wn.y, aN.y);
                    aN.z = fmaf(a, wn.z, aN.z); aN.w = fmaf(a, wn.w, aN.w);
                }
            }
            float iv = inv[n];
            float4 r;
            r.x = fmaxf(aS.x + iv * aN.x + bb.x, 0.f);
            r.y = fmaxf(aS.y + iv * aN.y + bb.y, 0.f);
            r.z = fmaxf(aS.z + iv * aN.z + bb.z, 0.f);
            r.w = fmaxf(aS.w + iv * aN.w + bb.w, 0.f);
            *(float4*)(out + (size_t)n * DOUT + q * 4) = r;
        }
    }
}

// ---------------- per-graph mean readout ----------------
__global__ void readout_graph(const float* __restrict__ h, const int* __restrict__ gid,
                              float* __restrict__ out) {
    const int g = blockIdx.x;
    const int t = threadIdx.x;
    int lo = 0, hi = NN;
    while (lo < hi) { int mid = (lo + hi) >> 1; if (gid[mid] < g) lo = mid + 1; else hi = mid; }
    const int start = lo;
    hi = NN;
    while (lo < hi) { int mid = (lo + hi) >> 1; if (gid[mid] <= g) lo = mid + 1; else hi = mid; }
    const int end = lo;

    float acc[5] = {0.f, 0.f, 0.f, 0.f, 0.f};
    for (int n = start + t; n < end; n += blockDim.x) {
        const float* row = h + (size_t)n * 5;
        #pragma unroll
        for (int j = 0; j < 5; ++j) acc[j] += row[j];
    }
    __shared__ float sh[5][256];
    #pragma unroll
    for (int j = 0; j < 5; ++j) sh[j][t] = acc[j];
    __syncthreads();
    for (int off = 128; off > 0; off >>= 1) {
        if (t < off) {
            #pragma unroll
            for (int j = 0; j < 5; ++j) sh[j][t] += sh[j][t + off];
        }
        __syncthreads();
    }
    if (t < 5) {
        float cnt = (float)(end - start);
        out[g * 5 + t] = sh[t][0] / fmaxf(cnt, 1.f);
    }
}

extern "C" void kernel_launch(void* const* d_in, const int* in_sizes, int n_in,
                              void* d_out, int out_size, void* d_ws, size_t ws_size,
                              hipStream_t stream) {
    const float* feat = (const float*)d_in[0];
    const int*   src  = (const int*)d_in[1];
    const int*   dst  = (const int*)d_in[2];
    const int*   gid  = (const int*)d_in[3];
    const float* Ws0 = (const float*)d_in[4],  *Wn0 = (const float*)d_in[5],  *b0 = (const float*)d_in[6];
    const float* Ws1 = (const float*)d_in[7],  *Wn1 = (const float*)d_in[8],  *b1 = (const float*)d_in[9];
    const float* Ws2 = (const float*)d_in[10], *Wn2 = (const float*)d_in[11], *b2 = (const float*)d_in[12];
    const float* Ws3 = (const float*)d_in[13], *Wn3 = (const float*)d_in[14], *b3 = (const float*)d_in[15];
    float* out = (float*)d_out;

    // ---- workspace layout ----
    float* ws   = (float*)d_ws;
    float* inv  = ws;                            // NN
    float* bufA = inv  + NN;                     // NN*128 f32 (h between layers)
    float* bufB = bufA + (size_t)NN * 128;       // NN*48 f32 (agg32 / hs) — pairs live here during build
    float* bufC = bufB + (size_t)NN * 48;        // NN*48 f32 region: fp16 tables / hn5 f32
    int*   deg     = (int*)(bufC + (size_t)NN * 48); // NN
    int*   row_ptr = deg + NN;                   // NN+1
    int*   bsum    = row_ptr + NN + 1;           // 256
    int*   bcnt    = bsum + 256;                 // NBKT
    int*   bbase   = bcnt + NBKT;                // NBKT
    int*   bcur    = bbase + NBKT;               // NBKT
    int*   csr_src = bcur + NBKT;                // NE
    unsigned int* pairs = (unsigned int*)bufB;   // NE packed (12.8 MB), dead after build
    half_t* hbuf  = (half_t*)bufC;               // fp16 gather tables (<= NN*48 halves)
    float*  hn5   = bufC;                        // f32 NN*5 for layer 3 (hbuf dead by then)

    const dim3 blk(256);

    // ---- CSR build: bucketed counting sort, packed ----
    hipMemsetAsync(bcnt, 0, NBKT * sizeof(int), stream);
    hist_bkt<<<512, blk, 0, stream>>>(dst, bcnt);
    scan_bkt<<<1, blk, 0, stream>>>(bcnt, bbase, bcur);
    partition_pairs<<<(NE + EPB - 1) / EPB, blk, 0, stream>>>(src, dst, bcur, pairs);
    bucket_deg<<<NBKT, blk, 0, stream>>>(pairs, bbase, bcur, deg, inv);
    chunk_sums<<<NB, blk, 0, stream>>>(deg, bsum);
    scan_bsums<<<1, blk, 0, stream>>>(bsum, row_ptr);
    scan_write<<<NB, blk, 0, stream>>>(deg, bsum, row_ptr);
    bucket_scatter<<<NBKT, blk, 0, stream>>>(pairs, bbase, bcur, row_ptr, csr_src);

    // ---- layer 0: feat->fp16, pull-aggregate 32 (half rows = 64B = 1 line), LDS-GEMM to 128 ----
    f32_to_h8<<<(NN * 4 + 255) / 256, blk, 0, stream>>>(feat, hbuf, NN * 4);
    gather_h<32, 4, 0><<<(NN + 63) / 64, blk, 0, stream>>>(
        row_ptr, csr_src, hbuf, nullptr, nullptr, nullptr, bufB);
    layer0_lds<<<(NN + 31) / 32, blk, 0, stream>>>(feat, bufB, Ws0, Wn0, b0, inv, bufA);

    // ---- layer 1: LDS-GEMM 128->48 (hs f32 + hn fp16), gather 48h (96B rows), combine ----
    proj_dual_lds_h<128, 128, 48, 48, 4><<<(NN + 83) / 84, blk, 0, stream>>>(
        bufA, Ws1, Wn1, bufB, hbuf);
    gather_h<48, 6, 1><<<(NN + 41) / 42, blk, 0, stream>>>(
        row_ptr, csr_src, hbuf, bufB, b1, inv, bufA);

    // ---- layer 2: LDS-GEMM 48->28 (padded to 32h = 64B rows), gather, combine ----
    proj_dual_lds_h<48, 48, 28, 32, 4><<<(NN + 143) / 144, blk, 0, stream>>>(
        bufA, Ws2, Wn2, bufB, hbuf);
    gather_h<32, 4, 2><<<(NN + 63) / 64, blk, 0, stream>>>(
        row_ptr, csr_src, hbuf, bufB, b2, inv, bufA);   // h2: stride 32, 28 real dims

    // ---- layer 3: 28->5 (dual f32, input stride 32), gather 5, combine (no relu) ----
    proj_dual_s<32, 28, 5><<<(NN * 5 + 255) / 256, blk, 0, stream>>>(bufA, Ws3, Wn3, bufB, hn5);
    gather_lds_s5<<<(NN + 50) / 51, blk, 0, stream>>>(row_ptr, csr_src, hn5, bufB, b3, inv, bufA);

    // ---- per-graph mean readout ----
    readout_graph<<<NG, blk, 0, stream>>>(bufA, gid, out);
}